// Round 3
// baseline (422.872 us; speedup 1.0000x reference)
//
#include <hip/hip_runtime.h>

#define IN_DIM 64
#define HID 64
#define HEADS 4
#define DD 256      // HID*HEADS
#define ENC_H 512
#define DUEL_H 128
#define NEG_SLOPE 0.2f

typedef _Float16 f16;
typedef __attribute__((ext_vector_type(2))) _Float16 f16x2;
typedef __attribute__((ext_vector_type(4))) _Float16 f16x4;
typedef __attribute__((ext_vector_type(8))) _Float16 f16x8;
typedef __attribute__((ext_vector_type(4))) float f32x4;

__device__ __forceinline__ f16x2 u2h(unsigned u) {
    union { unsigned u; f16x2 h; } c; c.u = u; return c.h;
}
__device__ __forceinline__ unsigned h2u(f16x2 h) {
    union { unsigned u; f16x2 h; } c; c.h = h; return c.u;
}

// ---------------- fused prep: cast x, transpose+cast weights, zero counts+bars ----------------

__global__ void prep_all(
    const float4* __restrict__ x, f16x4* __restrict__ x16, int nx4,
    const float* __restrict__ w1, const float* __restrict__ w2,
    const float* __restrict__ wl1, const float* __restrict__ wr1,
    const float* __restrict__ wl2, const float* __restrict__ wr2,
    f16* __restrict__ w1t, f16* __restrict__ w2t,
    f16* __restrict__ wcat1, f16* __restrict__ wcat2,
    int* __restrict__ counts, int ncnt, int* __restrict__ bars) {
    int i = blockIdx.x * blockDim.x + threadIdx.x;
    if (i < nx4) {
        float4 v = x[i];
        f16x4 o = {(f16)v.x, (f16)v.y, (f16)v.z, (f16)v.w};
        x16[i] = o;
        return;
    }
    i -= nx4;
    if (i < 229376) {
        if (i < 32768) {                       // w1 [64][512] -> w1t [512][64]
            int k = i >> 9, n = i & 511;
            w1t[n * 64 + k] = (f16)w1[i];
        } else if (i < 65536) {                // w2 [512][64] -> w2t [64][512]
            int j = i - 32768; int k = j >> 6, n = j & 63;
            w2t[n * 512 + k] = (f16)w2[j];
        } else if (i < 81920) {                // wl1 [64][256] -> wcat1[0..256)[64]
            int j = i - 65536; int k = j >> 8, n = j & 255;
            wcat1[n * 64 + k] = (f16)wl1[j];
        } else if (i < 98304) {                // wr1 -> wcat1[256..512)[64]
            int j = i - 81920; int k = j >> 8, n = j & 255;
            wcat1[(256 + n) * 64 + k] = (f16)wr1[j];
        } else if (i < 163840) {               // wl2 [256][256] -> wcat2[0..256)[256]
            int j = i - 98304; int k = j >> 8, n = j & 255;
            wcat2[n * 256 + k] = (f16)wl2[j];
        } else {                               // wr2 -> wcat2[256..512)[256]
            int j = i - 163840; int k = j >> 8, n = j & 255;
            wcat2[(256 + n) * 256 + k] = (f16)wr2[j];
        }
        return;
    }
    i -= 229376;
    if (i < ncnt) counts[i] = 0;
    else if (i < ncnt + 32) bars[i - ncnt] = 0;
}

// ---------------- fused CSR build: hist -> scan -> scatter, software grid barrier ----------------
// 256 blocks x 256 threads (1 block/CU -> co-resident). bars[0]=arrive, bars[16]=generation.
// Cross-XCD visibility: __threadfence around barrier + agent-scope atomic ld/st for
// scan intermediates (partials/offsets/cursor).

__device__ __forceinline__ void grid_barrier(int* __restrict__ bars, int nb) {
    __threadfence();
    __syncthreads();
    if (threadIdx.x == 0) {
        int* cnt = bars;
        int* gen = bars + 16;
        int g = __hip_atomic_load(gen, __ATOMIC_ACQUIRE, __HIP_MEMORY_SCOPE_AGENT);
        int a = __hip_atomic_fetch_add(cnt, 1, __ATOMIC_ACQ_REL, __HIP_MEMORY_SCOPE_AGENT);
        if (a == nb - 1) {
            __hip_atomic_store(cnt, 0, __ATOMIC_RELAXED, __HIP_MEMORY_SCOPE_AGENT);
            __hip_atomic_fetch_add(gen, 1, __ATOMIC_ACQ_REL, __HIP_MEMORY_SCOPE_AGENT);
        } else {
            while (__hip_atomic_load(gen, __ATOMIC_ACQUIRE, __HIP_MEMORY_SCOPE_AGENT) == g)
                __builtin_amdgcn_s_sleep(8);
        }
    }
    __syncthreads();
    __threadfence();
}

__global__ __launch_bounds__(256) void csr_build(
    const int* __restrict__ ei, int E, int N,
    int* __restrict__ counts, int* __restrict__ offsets,
    int* __restrict__ cursor, int* __restrict__ csr_src,
    int* __restrict__ partials, int* __restrict__ bars) {
    const int tid = threadIdx.x;
    const int nb = gridDim.x;
    const int gsize = nb * blockDim.x;
    const int gtid = blockIdx.x * blockDim.x + tid;
    const int Etot = E + N;
    const int lane = tid & 63, wid = tid >> 6;

    // ---- P1 histogram ----
    for (int e = gtid; e < Etot; e += gsize) {
        int dst = (e < E) ? ei[E + e] : (e - E);
        atomicAdd(&counts[dst], 1);
    }
    grid_barrier(bars, nb);

    // ---- P2a per-block partial sum over its chunk ----
    const int n = N + 1;
    const int chunk = (n + nb - 1) / nb;       // 79 for N=20000, nb=256
    const int base = blockIdx.x * chunk;
    int v = 0;
    if (tid < chunk && base + tid < n) v = counts[base + tid];
    __shared__ int lds[8];
    {
        int r = v;
        for (int off = 1; off < 64; off <<= 1) r += __shfl_xor(r, off);
        if (lane == 0) lds[wid] = r;
        __syncthreads();
        if (tid == 0) {
            int s = lds[0] + lds[1] + lds[2] + lds[3];
            __hip_atomic_store(&partials[blockIdx.x], s, __ATOMIC_RELAXED,
                               __HIP_MEMORY_SCOPE_AGENT);
        }
    }
    grid_barrier(bars, nb);

    // ---- P2c block prefix (sum partials[<b]) + block scan + write offsets/cursor ----
    {
        int pv = 0;
        if (tid < nb && tid < blockIdx.x)
            pv = __hip_atomic_load(&partials[tid], __ATOMIC_RELAXED,
                                   __HIP_MEMORY_SCOPE_AGENT);
        int pr = pv;
        for (int off = 1; off < 64; off <<= 1) pr += __shfl_xor(pr, off);
        if (lane == 0) lds[4 + wid] = pr;
        __syncthreads();
        int blockpref = lds[4] + lds[5] + lds[6] + lds[7];

        int sc = v;
        for (int off = 1; off < 64; off <<= 1) {
            int u = __shfl_up(sc, off);
            if (lane >= off) sc += u;
        }
        __shared__ int wtot[4];
        if (lane == 63) wtot[wid] = sc;
        __syncthreads();
        int wadd = 0;
        for (int w = 0; w < wid; ++w) wadd += wtot[w];
        int excl = blockpref + wadd + sc - v;
        if (tid < chunk && base + tid < n) {
            __hip_atomic_store(&offsets[base + tid], excl, __ATOMIC_RELAXED,
                               __HIP_MEMORY_SCOPE_AGENT);
            __hip_atomic_store(&cursor[base + tid], excl, __ATOMIC_RELAXED,
                               __HIP_MEMORY_SCOPE_AGENT);
        }
    }
    grid_barrier(bars, nb);

    // ---- P3 scatter ----
    for (int e = gtid; e < Etot; e += gsize) {
        int src, dst;
        if (e < E) { src = ei[e]; dst = ei[E + e]; }
        else       { src = e - E; dst = e - E; }
        int pos = atomicAdd(&cursor[dst], 1);
        csr_src[pos] = src;
    }
}

// ---------------- B-slab-resident fp16 MFMA GEMM, BM=64 ----------------

template <int K, int BN>
__global__ __launch_bounds__(256) void gemm_slab(
    const f16* __restrict__ A, const f16* __restrict__ Bt,
    const float* __restrict__ biasA, const float* __restrict__ biasB, int NS,
    int M, int relu,
    f16* __restrict__ C1, f16* __restrict__ C2) {
    constexpr int KS = K / 32;
    constexpr int PF = (KS < 8) ? KS : 8;      // deeper A prefetch (8 in flight)
    constexpr int COLW = BN / 2;
    constexpr int NT = COLW / 16;
    constexpr int SB = K + 8;
    constexpr int CE = COLW + 8;
    constexpr int SLABSZ = BN * SB;
    constexpr int EPISZ = 4 * 32 * CE;
    constexpr int SMEMSZ = (SLABSZ > EPISZ ? SLABSZ : EPISZ);

    __shared__ __align__(16) f16 smem[SMEMSZ];
    f16* Bs = smem;

    int tid = threadIdx.x;
    int wave = tid >> 6, lane = tid & 63;
    int quad = lane >> 4, l16 = lane & 15;
    int wr = wave >> 1, wc = wave & 1;
    int row0 = blockIdx.y * 64;
    int col0 = blockIdx.x * BN;

    constexpr int NCH = BN * K / 8;
#pragma unroll
    for (int i = 0; i < NCH / 256; ++i) {
        int c = tid + i * 256;
        int r = c / (K / 8), ko = (c % (K / 8)) * 8;
        uint4 v = *(const uint4*)&Bt[(size_t)(col0 + r) * K + ko];
        *(uint4*)&Bs[r * SB + ko] = v;
    }
    __syncthreads();

    const f16* Aptr[2];
#pragma unroll
    for (int mt = 0; mt < 2; ++mt) {
        int arow = row0 + wr * 32 + mt * 16 + l16;
        if (arow >= M) arow = M - 1;
        Aptr[mt] = &A[(size_t)arow * K + quad * 8];
    }

    f32x4 acc[2][NT];
#pragma unroll
    for (int mt = 0; mt < 2; ++mt)
#pragma unroll
        for (int j = 0; j < NT; ++j) acc[mt][j] = (f32x4){0.f, 0.f, 0.f, 0.f};

    f16x8 afb[2][PF];
#pragma unroll
    for (int mt = 0; mt < 2; ++mt)
#pragma unroll
        for (int i = 0; i < PF; ++i)
            afb[mt][i] = *(const f16x8*)&Aptr[mt][i * 32];

#pragma unroll
    for (int s = 0; s < KS; ++s) {
        f16x8 af0 = afb[0][s % PF], af1 = afb[1][s % PF];
        if (s + PF < KS) {
            afb[0][s % PF] = *(const f16x8*)&Aptr[0][(s + PF) * 32];
            afb[1][s % PF] = *(const f16x8*)&Aptr[1][(s + PF) * 32];
        }
        const f16* bbase = &Bs[(size_t)(wc * COLW) * SB + s * 32 + quad * 8];
#pragma unroll
        for (int nt = 0; nt < NT; ++nt) {
            f16x8 bf = *(const f16x8*)&bbase[(nt * 16 + l16) * SB];
            acc[0][nt] = __builtin_amdgcn_mfma_f32_16x16x32_f16(af0, bf, acc[0][nt], 0, 0, 0);
            acc[1][nt] = __builtin_amdgcn_mfma_f32_16x16x32_f16(af1, bf, acc[1][nt], 0, 0, 0);
        }
    }

    __syncthreads();
    f16* ep = &smem[wave * 32 * CE];
#pragma unroll
    for (int mt = 0; mt < 2; ++mt)
#pragma unroll
        for (int nt = 0; nt < NT; ++nt) {
            int gcol = col0 + wc * COLW + nt * 16 + l16;
            float bb = (gcol < NS) ? biasA[gcol] : biasB[gcol - NS];
#pragma unroll
            for (int r = 0; r < 4; ++r) {
                float v = acc[mt][nt][r] + bb;
                if (relu) v = fmaxf(v, 0.f);
                ep[(mt * 16 + quad * 4 + r) * CE + nt * 16 + l16] = (f16)v;
            }
        }
    constexpr int CPR = COLW / 8;
    constexpr int NPASS = (32 * CPR) / 64;
#pragma unroll
    for (int i = 0; i < NPASS; ++i) {
        int u = lane + i * 64;
        int row = u / CPR, seg = u % CPR;
        uint4 v = *(const uint4*)&ep[row * CE + seg * 8];
        int grow = row0 + wr * 32 + row;
        int gcol = col0 + wc * COLW + seg * 8;
        if (grow < M) {
            if (gcol < NS) *(uint4*)&C1[(size_t)grow * NS + gcol] = v;
            else           *(uint4*)&C2[(size_t)grow * NS + (gcol - NS)] = v;
        }
    }
}

// ---------------- fused GATv2: 1 node/wave, half-wave edge parity ----------------
// 32 lanes per half, each lane 8 dims (uint4); halves take alternating edges
// of the SAME node (no degree divergence). Head = 8-lane group; leaky fused
// into dot: att.leaky(t) = (.6 att).t + (.4 att).|t|. Cross-half combine via
// shfl_xor(32) at the end.

__global__ __launch_bounds__(256) void gat_fused_kernel(
    const uint4* __restrict__ xl, const uint4* __restrict__ xr,
    const float4* __restrict__ att,
    const int* __restrict__ offsets, const int* __restrict__ csr_src,
    const float4* __restrict__ bias, uint4* __restrict__ h16, int N) {
    int node = (blockIdx.x * blockDim.x + threadIdx.x) >> 6;
    int lane = threadIdx.x & 63;
    int half = lane >> 5, l32 = lane & 31;
    if (node >= N) return;
    int s = offsets[node], e = offsets[node + 1];
    uint4 xrw = xr[(size_t)node * 32 + l32];
    f16x2 xr0 = u2h(xrw.x), xr1 = u2h(xrw.y), xr2 = u2h(xrw.z), xr3 = u2h(xrw.w);
    float4 awA = att[l32 * 2], awB = att[l32 * 2 + 1];
    f16x2 a6[4] = {{(f16)(0.6f * awA.x), (f16)(0.6f * awA.y)},
                   {(f16)(0.6f * awA.z), (f16)(0.6f * awA.w)},
                   {(f16)(0.6f * awB.x), (f16)(0.6f * awB.y)},
                   {(f16)(0.6f * awB.z), (f16)(0.6f * awB.w)}};
    f16x2 a4[4] = {{(f16)(0.4f * awA.x), (f16)(0.4f * awA.y)},
                   {(f16)(0.4f * awA.z), (f16)(0.4f * awA.w)},
                   {(f16)(0.4f * awB.x), (f16)(0.4f * awB.y)},
                   {(f16)(0.4f * awB.z), (f16)(0.4f * awB.w)}};
    float denom = 0.f;
    float acc0 = 0.f, acc1 = 0.f, acc2 = 0.f, acc3 = 0.f;
    float acc4 = 0.f, acc5 = 0.f, acc6 = 0.f, acc7 = 0.f;

    auto edge_dot = [&](uint4 raw) -> float {
        f16x2 t0 = u2h(raw.x) + xr0, t1 = u2h(raw.y) + xr1;
        f16x2 t2 = u2h(raw.z) + xr2, t3 = u2h(raw.w) + xr3;
        float d = __builtin_amdgcn_fdot2(t0, a6[0], 0.f, false);
        d = __builtin_amdgcn_fdot2(u2h(h2u(t0) & 0x7FFF7FFFu), a4[0], d, false);
        d = __builtin_amdgcn_fdot2(t1, a6[1], d, false);
        d = __builtin_amdgcn_fdot2(u2h(h2u(t1) & 0x7FFF7FFFu), a4[1], d, false);
        d = __builtin_amdgcn_fdot2(t2, a6[2], d, false);
        d = __builtin_amdgcn_fdot2(u2h(h2u(t2) & 0x7FFF7FFFu), a4[2], d, false);
        d = __builtin_amdgcn_fdot2(t3, a6[3], d, false);
        d = __builtin_amdgcn_fdot2(u2h(h2u(t3) & 0x7FFF7FFFu), a4[3], d, false);
        return d;
    };
    auto accum = [&](uint4 raw, float ee) {
        f16x2 v0 = u2h(raw.x), v1 = u2h(raw.y), v2 = u2h(raw.z), v3 = u2h(raw.w);
        acc0 = fmaf(ee, (float)v0.x, acc0); acc1 = fmaf(ee, (float)v0.y, acc1);
        acc2 = fmaf(ee, (float)v1.x, acc2); acc3 = fmaf(ee, (float)v1.y, acc3);
        acc4 = fmaf(ee, (float)v2.x, acc4); acc5 = fmaf(ee, (float)v2.y, acc5);
        acc6 = fmaf(ee, (float)v3.x, acc6); acc7 = fmaf(ee, (float)v3.y, acc7);
    };

    int p = s + half;   // this half's first edge; halves interleave stride 2
    for (; p + 6 < e; p += 8) {
        uint4 raw[4];
#pragma unroll
        for (int j = 0; j < 4; ++j)
            raw[j] = xl[(size_t)csr_src[p + j * 2] * 32 + l32];
        float sc[4];
#pragma unroll
        for (int j = 0; j < 4; ++j) sc[j] = edge_dot(raw[j]);
#pragma unroll
        for (int j = 0; j < 4; ++j) sc[j] += __shfl_xor(sc[j], 1);
#pragma unroll
        for (int j = 0; j < 4; ++j) sc[j] += __shfl_xor(sc[j], 2);
#pragma unroll
        for (int j = 0; j < 4; ++j) sc[j] += __shfl_xor(sc[j], 4);
#pragma unroll
        for (int j = 0; j < 4; ++j) {
            float ee = __expf(sc[j]);
            denom += ee;
            accum(raw[j], ee);
        }
    }
    for (; p < e; p += 2) {
        uint4 raw = xl[(size_t)csr_src[p] * 32 + l32];
        float d = edge_dot(raw);
        d += __shfl_xor(d, 1);
        d += __shfl_xor(d, 2);
        d += __shfl_xor(d, 4);
        float ee = __expf(d);
        denom += ee;
        accum(raw, ee);
    }
    // combine halves
    denom += __shfl_xor(denom, 32);
    acc0 += __shfl_xor(acc0, 32); acc1 += __shfl_xor(acc1, 32);
    acc2 += __shfl_xor(acc2, 32); acc3 += __shfl_xor(acc3, 32);
    acc4 += __shfl_xor(acc4, 32); acc5 += __shfl_xor(acc5, 32);
    acc6 += __shfl_xor(acc6, 32); acc7 += __shfl_xor(acc7, 32);

    if (half == 0) {
        float inv = 1.f / (denom + 1e-16f);
        float4 bbA = bias[l32 * 2], bbB = bias[l32 * 2 + 1];
        float o0 = fmaxf(fmaf(acc0, inv, bbA.x), 0.f);
        float o1 = fmaxf(fmaf(acc1, inv, bbA.y), 0.f);
        float o2 = fmaxf(fmaf(acc2, inv, bbA.z), 0.f);
        float o3 = fmaxf(fmaf(acc3, inv, bbA.w), 0.f);
        float o4 = fmaxf(fmaf(acc4, inv, bbB.x), 0.f);
        float o5 = fmaxf(fmaf(acc5, inv, bbB.y), 0.f);
        float o6 = fmaxf(fmaf(acc6, inv, bbB.z), 0.f);
        float o7 = fmaxf(fmaf(acc7, inv, bbB.w), 0.f);
        f16x2 h0 = {(f16)o0, (f16)o1}, h1 = {(f16)o2, (f16)o3};
        f16x2 h2 = {(f16)o4, (f16)o5}, h3 = {(f16)o6, (f16)o7};
        uint4 outw = make_uint4(h2u(h0), h2u(h1), h2u(h2), h2u(h3));
        h16[(size_t)node * 32 + l32] = outw;
    }
}

// ---------------- dueling heads (f16 feature tables) ----------------

__global__ __launch_bounds__(256) void head_kernel(
    const f16* __restrict__ hE16, const f16* __restrict__ hC1_16,
    const f16* __restrict__ hC2_16, const int* __restrict__ indices,
    const float* __restrict__ qw1, const float* __restrict__ qb1,
    const float* __restrict__ qw2, const float* __restrict__ qb2,
    const float* __restrict__ vw1, const float* __restrict__ vb1,
    const float* __restrict__ vw2, const float* __restrict__ vb2,
    float* __restrict__ out) {
    __shared__ float feat[576];
    __shared__ float red[384];
    int b = blockIdx.x;
    int t = threadIdx.x;
    int node = indices[b];
    for (int i = t; i < 576; i += 256) {
        float f;
        if (i < 64) f = (float)hE16[(size_t)node * 64 + i];
        else if (i < 320) f = (float)hC1_16[(size_t)node * 256 + i - 64];
        else f = (float)hC2_16[(size_t)node * 256 + i - 320];
        feat[i] = f;
    }
    __syncthreads();
    if (t < 128) {
        float aq = qb1[t];
        for (int k = 0; k < 576; ++k)
            aq = fmaf(feat[k], qw1[k * 128 + t], aq);
        aq = fmaxf(aq, 0.f);
        red[t]       = aq * qw2[t * 2 + 0];
        red[128 + t] = aq * qw2[t * 2 + 1];
    } else {
        int tv = t - 128;
        float av = vb1[tv];
        for (int k = 0; k < 576; ++k)
            av = fmaf(feat[k], vw1[k * 128 + tv], av);
        av = fmaxf(av, 0.f);
        red[256 + tv] = av * vw2[tv];
    }
    __syncthreads();
    for (int s = 64; s > 0; s >>= 1) {
        if (t < s) {
            red[t] += red[t + s];
            red[128 + t] += red[128 + t + s];
            red[256 + t] += red[256 + t + s];
        }
        __syncthreads();
    }
    if (t == 0) {
        float q0 = red[0] + qb2[0];
        float q1 = red[128] + qb2[1];
        float v  = red[256] + vb2[0];
        float mean = 0.5f * (q0 + q1);
        out[b * 2 + 0] = q0 - mean + v;
        out[b * 2 + 1] = q1 - mean + v;
    }
}

// ---------------- launch ----------------

extern "C" void kernel_launch(void* const* d_in, const int* in_sizes, int n_in,
                              void* d_out, int out_size, void* d_ws, size_t ws_size,
                              hipStream_t stream) {
    const float* x      = (const float*)d_in[0];
    const int*   ei     = (const int*)d_in[1];
    const int*   indices= (const int*)d_in[2];
    const float* enc_w1 = (const float*)d_in[3];
    const float* enc_b1 = (const float*)d_in[4];
    const float* enc_w2 = (const float*)d_in[5];
    const float* enc_b2 = (const float*)d_in[6];
    const float* wl1    = (const float*)d_in[7];
    const float* bl1    = (const float*)d_in[8];
    const float* wr1    = (const float*)d_in[9];
    const float* br1    = (const float*)d_in[10];
    const float* att1   = (const float*)d_in[11];
    const float* bias1  = (const float*)d_in[12];
    const float* wl2    = (const float*)d_in[13];
    const float* bl2    = (const float*)d_in[14];
    const float* wr2    = (const float*)d_in[15];
    const float* br2    = (const float*)d_in[16];
    const float* att2   = (const float*)d_in[17];
    const float* bias2  = (const float*)d_in[18];
    const float* qw1    = (const float*)d_in[19];
    const float* qb1    = (const float*)d_in[20];
    const float* qw2    = (const float*)d_in[21];
    const float* qb2    = (const float*)d_in[22];
    const float* vw1    = (const float*)d_in[23];
    const float* vb1    = (const float*)d_in[24];
    const float* vw2    = (const float*)d_in[25];
    const float* vb2    = (const float*)d_in[26];

    const int N = in_sizes[0] / IN_DIM;
    const int E = in_sizes[1] / 2;
    const int B = in_sizes[2];
    const int Etot = E + N;

    // ---- workspace arena ----
    char* wsb = (char*)d_ws;
    size_t off = 0;
    auto alloc = [&](size_t bytes) -> void* {
        void* p = wsb + off;
        off = (off + bytes + 255) & ~(size_t)255;
        return p;
    };
    f16* x16     = (f16*)alloc((size_t)N * 64 * 2);
    f16* h1_16   = (f16*)alloc((size_t)N * 512 * 2);
    f16* hE16    = (f16*)alloc((size_t)N * 64 * 2);
    f16* xl16    = (f16*)alloc((size_t)N * 256 * 2);
    f16* xr16    = (f16*)alloc((size_t)N * 256 * 2);
    f16* hC1_16  = (f16*)alloc((size_t)N * 256 * 2);
    f16* hC2_16  = (f16*)alloc((size_t)N * 256 * 2);
    f16* w1t     = (f16*)alloc((size_t)ENC_H * IN_DIM * 2);
    f16* w2t     = (f16*)alloc((size_t)HID * ENC_H * 2);
    f16* wcat1   = (f16*)alloc((size_t)512 * HID * 2);
    f16* wcat2   = (f16*)alloc((size_t)512 * DD * 2);
    int* counts  = (int*)alloc((size_t)(N + 1) * 4);
    int* offsets = (int*)alloc((size_t)(N + 1) * 4);
    int* cursor  = (int*)alloc((size_t)(N + 1) * 4);
    int* csr_src = (int*)alloc((size_t)Etot * 4);
    int* partials= (int*)alloc((size_t)256 * 4);
    int* bars    = (int*)alloc((size_t)32 * 4);

    // ---- prep (also zeroes counts + barrier words) ----
    int nx4 = N * 16;
    int ntot = nx4 + 229376 + (N + 1) + 32;
    prep_all<<<(ntot + 255) / 256, 256, 0, stream>>>(
        (const float4*)x, (f16x4*)x16, nx4,
        enc_w1, enc_w2, wl1, wr1, wl2, wr2,
        w1t, w2t, wcat1, wcat2, counts, N + 1, bars);

    // ---- fused CSR build (hist + scan + scatter, 3 grid barriers) ----
    csr_build<<<256, 256, 0, stream>>>(ei, E, N, counts, offsets, cursor,
                                       csr_src, partials, bars);

    dim3 blk(256);
    int grows = (N + 63) / 64;   // 313

    // encoder
    gemm_slab<64, 128><<<dim3(4, grows), blk, 0, stream>>>(
        x16, w1t, enc_b1, enc_b1, 512, N, 1, h1_16, h1_16);
    gemm_slab<512, 64><<<dim3(1, grows), blk, 0, stream>>>(
        h1_16, w2t, enc_b2, enc_b2, 64, N, 1, hE16, hE16);

    // conv1 transform + GAT
    gemm_slab<64, 128><<<dim3(4, grows), blk, 0, stream>>>(
        hE16, wcat1, bl1, br1, DD, N, 0, xl16, xr16);
    int gatg = (N * 64 + 255) / 256;
    gat_fused_kernel<<<gatg, 256, 0, stream>>>(
        (const uint4*)xl16, (const uint4*)xr16, (const float4*)att1,
        offsets, csr_src, (const float4*)bias1, (uint4*)hC1_16, N);

    // conv2 transform + GAT
    gemm_slab<256, 128><<<dim3(4, grows), blk, 0, stream>>>(
        hC1_16, wcat2, bl2, br2, DD, N, 0, xl16, xr16);
    gat_fused_kernel<<<gatg, 256, 0, stream>>>(
        (const uint4*)xl16, (const uint4*)xr16, (const float4*)att2,
        offsets, csr_src, (const float4*)bias2, (uint4*)hC2_16, N);

    // dueling heads
    head_kernel<<<B, 256, 0, stream>>>(hE16, hC1_16, hC2_16, indices,
                                       qw1, qb1, qw2, qb2, vw1, vb1, vw2, vb2,
                                       (float*)d_out);
}

// Round 4
// 313.875 us; speedup vs baseline: 1.3473x; 1.3473x over previous
//
#include <hip/hip_runtime.h>

#define IN_DIM 64
#define HID 64
#define HEADS 4
#define DD 256      // HID*HEADS
#define ENC_H 512
#define DUEL_H 128
#define NEG_SLOPE 0.2f

typedef _Float16 f16;
typedef __attribute__((ext_vector_type(2))) _Float16 f16x2;
typedef __attribute__((ext_vector_type(4))) _Float16 f16x4;
typedef __attribute__((ext_vector_type(8))) _Float16 f16x8;
typedef __attribute__((ext_vector_type(4))) float f32x4;

__device__ __forceinline__ f16x2 u2h(unsigned u) {
    union { unsigned u; f16x2 h; } c; c.u = u; return c.h;
}
__device__ __forceinline__ unsigned h2u(f16x2 h) {
    union { unsigned u; f16x2 h; } c; c.h = h; return c.u;
}

// ---------------- fused prep: cast x, transpose+cast weights, zero counts+done ----------------

__global__ void prep_all(
    const float4* __restrict__ x, f16x4* __restrict__ x16, int nx4,
    const float* __restrict__ w1, const float* __restrict__ w2,
    const float* __restrict__ wl1, const float* __restrict__ wr1,
    const float* __restrict__ wl2, const float* __restrict__ wr2,
    f16* __restrict__ w1t, f16* __restrict__ w2t,
    f16* __restrict__ wcat1, f16* __restrict__ wcat2,
    int* __restrict__ counts, int ncnt, int* __restrict__ bars) {
    int i = blockIdx.x * blockDim.x + threadIdx.x;
    if (i < nx4) {
        float4 v = x[i];
        f16x4 o = {(f16)v.x, (f16)v.y, (f16)v.z, (f16)v.w};
        x16[i] = o;
        return;
    }
    i -= nx4;
    if (i < 229376) {
        if (i < 32768) {                       // w1 [64][512] -> w1t [512][64]
            int k = i >> 9, n = i & 511;
            w1t[n * 64 + k] = (f16)w1[i];
        } else if (i < 65536) {                // w2 [512][64] -> w2t [64][512]
            int j = i - 32768; int k = j >> 6, n = j & 63;
            w2t[n * 512 + k] = (f16)w2[j];
        } else if (i < 81920) {                // wl1 [64][256] -> wcat1[0..256)[64]
            int j = i - 65536; int k = j >> 8, n = j & 255;
            wcat1[n * 64 + k] = (f16)wl1[j];
        } else if (i < 98304) {                // wr1 -> wcat1[256..512)[64]
            int j = i - 81920; int k = j >> 8, n = j & 255;
            wcat1[(256 + n) * 64 + k] = (f16)wr1[j];
        } else if (i < 163840) {               // wl2 [256][256] -> wcat2[0..256)[256]
            int j = i - 98304; int k = j >> 8, n = j & 255;
            wcat2[n * 256 + k] = (f16)wl2[j];
        } else {                               // wr2 -> wcat2[256..512)[256]
            int j = i - 163840; int k = j >> 8, n = j & 255;
            wcat2[(256 + n) * 256 + k] = (f16)wr2[j];
        }
        return;
    }
    i -= 229376;
    if (i < ncnt) counts[i] = 0;
    else if (i < ncnt + 32) bars[i - ncnt] = 0;
}

// ---------------- fused hist + scan (last-block-done, no spinning) ----------------
// All blocks histogram their slice; the LAST block to finish (detected via a
// device-scope done-counter) performs the full exclusive scan of counts into
// offsets/cursor. No block ever waits on another block -> safe under any
// dispatch order / occupancy. counts reads in the scan use agent-scope atomic
// loads for cross-XCD visibility of other blocks' atomicAdds.

__global__ __launch_bounds__(1024) void hist_scan_kernel(
    const int* __restrict__ ei, int E, int N,
    int* __restrict__ counts, int* __restrict__ offsets,
    int* __restrict__ cursor, int* __restrict__ done) {
    const int Etot = E + N;
    int e = blockIdx.x * 1024 + threadIdx.x;
    if (e < Etot) {
        int dst = (e < E) ? ei[E + e] : (e - E);
        atomicAdd(&counts[dst], 1);
    }
    __shared__ bool amLast;
    __syncthreads();
    if (threadIdx.x == 0) {
        __threadfence();   // publish this block's histogram atomics
        int d = __hip_atomic_fetch_add(done, 1, __ATOMIC_ACQ_REL,
                                       __HIP_MEMORY_SCOPE_AGENT);
        amLast = (d == (int)gridDim.x - 1);
    }
    __syncthreads();
    if (!amLast) return;
    __threadfence();       // acquire side before reading counts

    // ---- exclusive scan of counts[0..n) -> offsets/cursor; offsets[n] = total ----
    const int n = N + 1;
    __shared__ int wsum[16];
    int t = threadIdx.x;
    int chunk = (n + 1023) / 1024;
    int b0 = t * chunk;
    int b1 = b0 + chunk; if (b1 > n) b1 = n;
    if (b0 > n) b0 = n;
    int sum = 0;
    for (int i = b0; i < b1; ++i)
        sum += __hip_atomic_load(&counts[i], __ATOMIC_RELAXED,
                                 __HIP_MEMORY_SCOPE_AGENT);
    int lane = t & 63, wid = t >> 6;
    int v = sum;
    for (int off = 1; off < 64; off <<= 1) {
        int u = __shfl_up(v, off);
        if (lane >= off) v += u;
    }
    if (lane == 63) wsum[wid] = v;
    __syncthreads();
    if (wid == 0) {
        int wv = (lane < 16) ? wsum[lane] : 0;
        for (int off = 1; off < 16; off <<= 1) {
            int u = __shfl_up(wv, off);
            if (lane >= off) wv += u;
        }
        if (lane < 16) wsum[lane] = wv;
    }
    __syncthreads();
    int excl = v - sum + (wid > 0 ? wsum[wid - 1] : 0);
    int run = excl;
    for (int i = b0; i < b1; ++i) {
        int c = __hip_atomic_load(&counts[i], __ATOMIC_RELAXED,
                                  __HIP_MEMORY_SCOPE_AGENT);
        offsets[i] = run; cursor[i] = run;
        run += c;
    }
    if (t == 1023) offsets[n] = wsum[15];
}

__global__ void scatter_kernel(const int* __restrict__ ei, int E, int N,
                               int* cursor, int* csr_src) {
    int e = blockIdx.x * blockDim.x + threadIdx.x;
    int Etot = E + N;
    if (e >= Etot) return;
    int src, dst;
    if (e < E) { src = ei[e]; dst = ei[E + e]; }
    else       { src = e - E; dst = e - E; }
    int pos = atomicAdd(&cursor[dst], 1);
    csr_src[pos] = src;
}

// ---------------- B-slab-resident fp16 MFMA GEMM, BM=64 ----------------

template <int K, int BN>
__global__ __launch_bounds__(256) void gemm_slab(
    const f16* __restrict__ A, const f16* __restrict__ Bt,
    const float* __restrict__ biasA, const float* __restrict__ biasB, int NS,
    int M, int relu,
    f16* __restrict__ C1, f16* __restrict__ C2) {
    constexpr int KS = K / 32;
    constexpr int PF = (KS < 8) ? KS : 8;      // deeper A prefetch (8 in flight)
    constexpr int COLW = BN / 2;
    constexpr int NT = COLW / 16;
    constexpr int SB = K + 8;
    constexpr int CE = COLW + 8;
    constexpr int SLABSZ = BN * SB;
    constexpr int EPISZ = 4 * 32 * CE;
    constexpr int SMEMSZ = (SLABSZ > EPISZ ? SLABSZ : EPISZ);

    __shared__ __align__(16) f16 smem[SMEMSZ];
    f16* Bs = smem;

    int tid = threadIdx.x;
    int wave = tid >> 6, lane = tid & 63;
    int quad = lane >> 4, l16 = lane & 15;
    int wr = wave >> 1, wc = wave & 1;
    int row0 = blockIdx.y * 64;
    int col0 = blockIdx.x * BN;

    constexpr int NCH = BN * K / 8;
#pragma unroll
    for (int i = 0; i < NCH / 256; ++i) {
        int c = tid + i * 256;
        int r = c / (K / 8), ko = (c % (K / 8)) * 8;
        uint4 v = *(const uint4*)&Bt[(size_t)(col0 + r) * K + ko];
        *(uint4*)&Bs[r * SB + ko] = v;
    }
    __syncthreads();

    const f16* Aptr[2];
#pragma unroll
    for (int mt = 0; mt < 2; ++mt) {
        int arow = row0 + wr * 32 + mt * 16 + l16;
        if (arow >= M) arow = M - 1;
        Aptr[mt] = &A[(size_t)arow * K + quad * 8];
    }

    f32x4 acc[2][NT];
#pragma unroll
    for (int mt = 0; mt < 2; ++mt)
#pragma unroll
        for (int j = 0; j < NT; ++j) acc[mt][j] = (f32x4){0.f, 0.f, 0.f, 0.f};

    f16x8 afb[2][PF];
#pragma unroll
    for (int mt = 0; mt < 2; ++mt)
#pragma unroll
        for (int i = 0; i < PF; ++i)
            afb[mt][i] = *(const f16x8*)&Aptr[mt][i * 32];

#pragma unroll
    for (int s = 0; s < KS; ++s) {
        f16x8 af0 = afb[0][s % PF], af1 = afb[1][s % PF];
        if (s + PF < KS) {
            afb[0][s % PF] = *(const f16x8*)&Aptr[0][(s + PF) * 32];
            afb[1][s % PF] = *(const f16x8*)&Aptr[1][(s + PF) * 32];
        }
        const f16* bbase = &Bs[(size_t)(wc * COLW) * SB + s * 32 + quad * 8];
#pragma unroll
        for (int nt = 0; nt < NT; ++nt) {
            f16x8 bf = *(const f16x8*)&bbase[(nt * 16 + l16) * SB];
            acc[0][nt] = __builtin_amdgcn_mfma_f32_16x16x32_f16(af0, bf, acc[0][nt], 0, 0, 0);
            acc[1][nt] = __builtin_amdgcn_mfma_f32_16x16x32_f16(af1, bf, acc[1][nt], 0, 0, 0);
        }
    }

    __syncthreads();
    f16* ep = &smem[wave * 32 * CE];
#pragma unroll
    for (int mt = 0; mt < 2; ++mt)
#pragma unroll
        for (int nt = 0; nt < NT; ++nt) {
            int gcol = col0 + wc * COLW + nt * 16 + l16;
            float bb = (gcol < NS) ? biasA[gcol] : biasB[gcol - NS];
#pragma unroll
            for (int r = 0; r < 4; ++r) {
                float v = acc[mt][nt][r] + bb;
                if (relu) v = fmaxf(v, 0.f);
                ep[(mt * 16 + quad * 4 + r) * CE + nt * 16 + l16] = (f16)v;
            }
        }
    constexpr int CPR = COLW / 8;
    constexpr int NPASS = (32 * CPR) / 64;
#pragma unroll
    for (int i = 0; i < NPASS; ++i) {
        int u = lane + i * 64;
        int row = u / CPR, seg = u % CPR;
        uint4 v = *(const uint4*)&ep[row * CE + seg * 8];
        int grow = row0 + wr * 32 + row;
        int gcol = col0 + wc * COLW + seg * 8;
        if (grow < M) {
            if (gcol < NS) *(uint4*)&C1[(size_t)grow * NS + gcol] = v;
            else           *(uint4*)&C2[(size_t)grow * NS + (gcol - NS)] = v;
        }
    }
}

// ---------------- fused GATv2: 1 node/wave, half-wave edge parity ----------------
// 32 lanes per half, each lane 8 dims (uint4); halves take alternating edges
// of the SAME node (no degree divergence). Head = 8-lane group; leaky fused
// into dot: att.leaky(t) = (.6 att).t + (.4 att).|t|. Cross-half combine via
// shfl_xor(32) at the end.

__global__ __launch_bounds__(256) void gat_fused_kernel(
    const uint4* __restrict__ xl, const uint4* __restrict__ xr,
    const float4* __restrict__ att,
    const int* __restrict__ offsets, const int* __restrict__ csr_src,
    const float4* __restrict__ bias, uint4* __restrict__ h16, int N) {
    int node = (blockIdx.x * blockDim.x + threadIdx.x) >> 6;
    int lane = threadIdx.x & 63;
    int half = lane >> 5, l32 = lane & 31;
    if (node >= N) return;
    int s = offsets[node], e = offsets[node + 1];
    uint4 xrw = xr[(size_t)node * 32 + l32];
    f16x2 xr0 = u2h(xrw.x), xr1 = u2h(xrw.y), xr2 = u2h(xrw.z), xr3 = u2h(xrw.w);
    float4 awA = att[l32 * 2], awB = att[l32 * 2 + 1];
    f16x2 a6[4] = {{(f16)(0.6f * awA.x), (f16)(0.6f * awA.y)},
                   {(f16)(0.6f * awA.z), (f16)(0.6f * awA.w)},
                   {(f16)(0.6f * awB.x), (f16)(0.6f * awB.y)},
                   {(f16)(0.6f * awB.z), (f16)(0.6f * awB.w)}};
    f16x2 a4[4] = {{(f16)(0.4f * awA.x), (f16)(0.4f * awA.y)},
                   {(f16)(0.4f * awA.z), (f16)(0.4f * awA.w)},
                   {(f16)(0.4f * awB.x), (f16)(0.4f * awB.y)},
                   {(f16)(0.4f * awB.z), (f16)(0.4f * awB.w)}};
    float denom = 0.f;
    float acc0 = 0.f, acc1 = 0.f, acc2 = 0.f, acc3 = 0.f;
    float acc4 = 0.f, acc5 = 0.f, acc6 = 0.f, acc7 = 0.f;

    auto edge_dot = [&](uint4 raw) -> float {
        f16x2 t0 = u2h(raw.x) + xr0, t1 = u2h(raw.y) + xr1;
        f16x2 t2 = u2h(raw.z) + xr2, t3 = u2h(raw.w) + xr3;
        float d = __builtin_amdgcn_fdot2(t0, a6[0], 0.f, false);
        d = __builtin_amdgcn_fdot2(u2h(h2u(t0) & 0x7FFF7FFFu), a4[0], d, false);
        d = __builtin_amdgcn_fdot2(t1, a6[1], d, false);
        d = __builtin_amdgcn_fdot2(u2h(h2u(t1) & 0x7FFF7FFFu), a4[1], d, false);
        d = __builtin_amdgcn_fdot2(t2, a6[2], d, false);
        d = __builtin_amdgcn_fdot2(u2h(h2u(t2) & 0x7FFF7FFFu), a4[2], d, false);
        d = __builtin_amdgcn_fdot2(t3, a6[3], d, false);
        d = __builtin_amdgcn_fdot2(u2h(h2u(t3) & 0x7FFF7FFFu), a4[3], d, false);
        return d;
    };
    auto accum = [&](uint4 raw, float ee) {
        f16x2 v0 = u2h(raw.x), v1 = u2h(raw.y), v2 = u2h(raw.z), v3 = u2h(raw.w);
        acc0 = fmaf(ee, (float)v0.x, acc0); acc1 = fmaf(ee, (float)v0.y, acc1);
        acc2 = fmaf(ee, (float)v1.x, acc2); acc3 = fmaf(ee, (float)v1.y, acc3);
        acc4 = fmaf(ee, (float)v2.x, acc4); acc5 = fmaf(ee, (float)v2.y, acc5);
        acc6 = fmaf(ee, (float)v3.x, acc6); acc7 = fmaf(ee, (float)v3.y, acc7);
    };

    int p = s + half;   // this half's first edge; halves interleave stride 2
    for (; p + 6 < e; p += 8) {
        uint4 raw[4];
#pragma unroll
        for (int j = 0; j < 4; ++j)
            raw[j] = xl[(size_t)csr_src[p + j * 2] * 32 + l32];
        float sc[4];
#pragma unroll
        for (int j = 0; j < 4; ++j) sc[j] = edge_dot(raw[j]);
#pragma unroll
        for (int j = 0; j < 4; ++j) sc[j] += __shfl_xor(sc[j], 1);
#pragma unroll
        for (int j = 0; j < 4; ++j) sc[j] += __shfl_xor(sc[j], 2);
#pragma unroll
        for (int j = 0; j < 4; ++j) sc[j] += __shfl_xor(sc[j], 4);
#pragma unroll
        for (int j = 0; j < 4; ++j) {
            float ee = __expf(sc[j]);
            denom += ee;
            accum(raw[j], ee);
        }
    }
    for (; p < e; p += 2) {
        uint4 raw = xl[(size_t)csr_src[p] * 32 + l32];
        float d = edge_dot(raw);
        d += __shfl_xor(d, 1);
        d += __shfl_xor(d, 2);
        d += __shfl_xor(d, 4);
        float ee = __expf(d);
        denom += ee;
        accum(raw, ee);
    }
    // combine halves
    denom += __shfl_xor(denom, 32);
    acc0 += __shfl_xor(acc0, 32); acc1 += __shfl_xor(acc1, 32);
    acc2 += __shfl_xor(acc2, 32); acc3 += __shfl_xor(acc3, 32);
    acc4 += __shfl_xor(acc4, 32); acc5 += __shfl_xor(acc5, 32);
    acc6 += __shfl_xor(acc6, 32); acc7 += __shfl_xor(acc7, 32);

    if (half == 0) {
        float inv = 1.f / (denom + 1e-16f);
        float4 bbA = bias[l32 * 2], bbB = bias[l32 * 2 + 1];
        float o0 = fmaxf(fmaf(acc0, inv, bbA.x), 0.f);
        float o1 = fmaxf(fmaf(acc1, inv, bbA.y), 0.f);
        float o2 = fmaxf(fmaf(acc2, inv, bbA.z), 0.f);
        float o3 = fmaxf(fmaf(acc3, inv, bbA.w), 0.f);
        float o4 = fmaxf(fmaf(acc4, inv, bbB.x), 0.f);
        float o5 = fmaxf(fmaf(acc5, inv, bbB.y), 0.f);
        float o6 = fmaxf(fmaf(acc6, inv, bbB.z), 0.f);
        float o7 = fmaxf(fmaf(acc7, inv, bbB.w), 0.f);
        f16x2 h0 = {(f16)o0, (f16)o1}, h1 = {(f16)o2, (f16)o3};
        f16x2 h2 = {(f16)o4, (f16)o5}, h3 = {(f16)o6, (f16)o7};
        uint4 outw = make_uint4(h2u(h0), h2u(h1), h2u(h2), h2u(h3));
        h16[(size_t)node * 32 + l32] = outw;
    }
}

// ---------------- dueling heads (f16 feature tables) ----------------

__global__ __launch_bounds__(256) void head_kernel(
    const f16* __restrict__ hE16, const f16* __restrict__ hC1_16,
    const f16* __restrict__ hC2_16, const int* __restrict__ indices,
    const float* __restrict__ qw1, const float* __restrict__ qb1,
    const float* __restrict__ qw2, const float* __restrict__ qb2,
    const float* __restrict__ vw1, const float* __restrict__ vb1,
    const float* __restrict__ vw2, const float* __restrict__ vb2,
    float* __restrict__ out) {
    __shared__ float feat[576];
    __shared__ float red[384];
    int b = blockIdx.x;
    int t = threadIdx.x;
    int node = indices[b];
    for (int i = t; i < 576; i += 256) {
        float f;
        if (i < 64) f = (float)hE16[(size_t)node * 64 + i];
        else if (i < 320) f = (float)hC1_16[(size_t)node * 256 + i - 64];
        else f = (float)hC2_16[(size_t)node * 256 + i - 320];
        feat[i] = f;
    }
    __syncthreads();
    if (t < 128) {
        float aq = qb1[t];
        for (int k = 0; k < 576; ++k)
            aq = fmaf(feat[k], qw1[k * 128 + t], aq);
        aq = fmaxf(aq, 0.f);
        red[t]       = aq * qw2[t * 2 + 0];
        red[128 + t] = aq * qw2[t * 2 + 1];
    } else {
        int tv = t - 128;
        float av = vb1[tv];
        for (int k = 0; k < 576; ++k)
            av = fmaf(feat[k], vw1[k * 128 + tv], av);
        av = fmaxf(av, 0.f);
        red[256 + tv] = av * vw2[tv];
    }
    __syncthreads();
    for (int s = 64; s > 0; s >>= 1) {
        if (t < s) {
            red[t] += red[t + s];
            red[128 + t] += red[128 + t + s];
            red[256 + t] += red[256 + t + s];
        }
        __syncthreads();
    }
    if (t == 0) {
        float q0 = red[0] + qb2[0];
        float q1 = red[128] + qb2[1];
        float v  = red[256] + vb2[0];
        float mean = 0.5f * (q0 + q1);
        out[b * 2 + 0] = q0 - mean + v;
        out[b * 2 + 1] = q1 - mean + v;
    }
}

// ---------------- launch ----------------

extern "C" void kernel_launch(void* const* d_in, const int* in_sizes, int n_in,
                              void* d_out, int out_size, void* d_ws, size_t ws_size,
                              hipStream_t stream) {
    const float* x      = (const float*)d_in[0];
    const int*   ei     = (const int*)d_in[1];
    const int*   indices= (const int*)d_in[2];
    const float* enc_w1 = (const float*)d_in[3];
    const float* enc_b1 = (const float*)d_in[4];
    const float* enc_w2 = (const float*)d_in[5];
    const float* enc_b2 = (const float*)d_in[6];
    const float* wl1    = (const float*)d_in[7];
    const float* bl1    = (const float*)d_in[8];
    const float* wr1    = (const float*)d_in[9];
    const float* br1    = (const float*)d_in[10];
    const float* att1   = (const float*)d_in[11];
    const float* bias1  = (const float*)d_in[12];
    const float* wl2    = (const float*)d_in[13];
    const float* bl2    = (const float*)d_in[14];
    const float* wr2    = (const float*)d_in[15];
    const float* br2    = (const float*)d_in[16];
    const float* att2   = (const float*)d_in[17];
    const float* bias2  = (const float*)d_in[18];
    const float* qw1    = (const float*)d_in[19];
    const float* qb1    = (const float*)d_in[20];
    const float* qw2    = (const float*)d_in[21];
    const float* qb2    = (const float*)d_in[22];
    const float* vw1    = (const float*)d_in[23];
    const float* vb1    = (const float*)d_in[24];
    const float* vw2    = (const float*)d_in[25];
    const float* vb2    = (const float*)d_in[26];

    const int N = in_sizes[0] / IN_DIM;
    const int E = in_sizes[1] / 2;
    const int B = in_sizes[2];
    const int Etot = E + N;

    // ---- workspace arena ----
    char* wsb = (char*)d_ws;
    size_t off = 0;
    auto alloc = [&](size_t bytes) -> void* {
        void* p = wsb + off;
        off = (off + bytes + 255) & ~(size_t)255;
        return p;
    };
    f16* x16     = (f16*)alloc((size_t)N * 64 * 2);
    f16* h1_16   = (f16*)alloc((size_t)N * 512 * 2);
    f16* hE16    = (f16*)alloc((size_t)N * 64 * 2);
    f16* xl16    = (f16*)alloc((size_t)N * 256 * 2);
    f16* xr16    = (f16*)alloc((size_t)N * 256 * 2);
    f16* hC1_16  = (f16*)alloc((size_t)N * 256 * 2);
    f16* hC2_16  = (f16*)alloc((size_t)N * 256 * 2);
    f16* w1t     = (f16*)alloc((size_t)ENC_H * IN_DIM * 2);
    f16* w2t     = (f16*)alloc((size_t)HID * ENC_H * 2);
    f16* wcat1   = (f16*)alloc((size_t)512 * HID * 2);
    f16* wcat2   = (f16*)alloc((size_t)512 * DD * 2);
    int* counts  = (int*)alloc((size_t)(N + 1) * 4);
    int* offsets = (int*)alloc((size_t)(N + 1) * 4);
    int* cursor  = (int*)alloc((size_t)(N + 1) * 4);
    int* csr_src = (int*)alloc((size_t)Etot * 4);
    int* bars    = (int*)alloc((size_t)32 * 4);

    // ---- prep (also zeroes counts + done counter) ----
    int nx4 = N * 16;
    int ntot = nx4 + 229376 + (N + 1) + 32;
    prep_all<<<(ntot + 255) / 256, 256, 0, stream>>>(
        (const float4*)x, (f16x4*)x16, nx4,
        enc_w1, enc_w2, wl1, wr1, wl2, wr2,
        w1t, w2t, wcat1, wcat2, counts, N + 1, bars);

    // ---- CSR by dst: fused hist+scan (last-block-done), then scatter ----
    hist_scan_kernel<<<(Etot + 1023) / 1024, 1024, 0, stream>>>(
        ei, E, N, counts, offsets, cursor, bars);
    scatter_kernel<<<(Etot + 255) / 256, 256, 0, stream>>>(ei, E, N, cursor, csr_src);

    dim3 blk(256);
    int grows = (N + 63) / 64;   // 313

    // encoder
    gemm_slab<64, 128><<<dim3(4, grows), blk, 0, stream>>>(
        x16, w1t, enc_b1, enc_b1, 512, N, 1, h1_16, h1_16);
    gemm_slab<512, 64><<<dim3(1, grows), blk, 0, stream>>>(
        h1_16, w2t, enc_b2, enc_b2, 64, N, 1, hE16, hE16);

    // conv1 transform + GAT
    gemm_slab<64, 128><<<dim3(4, grows), blk, 0, stream>>>(
        hE16, wcat1, bl1, br1, DD, N, 0, xl16, xr16);
    int gatg = (N * 64 + 255) / 256;
    gat_fused_kernel<<<gatg, 256, 0, stream>>>(
        (const uint4*)xl16, (const uint4*)xr16, (const float4*)att1,
        offsets, csr_src, (const float4*)bias1, (uint4*)hC1_16, N);

    // conv2 transform + GAT
    gemm_slab<256, 128><<<dim3(4, grows), blk, 0, stream>>>(
        hC1_16, wcat2, bl2, br2, DD, N, 0, xl16, xr16);
    gat_fused_kernel<<<gatg, 256, 0, stream>>>(
        (const uint4*)xl16, (const uint4*)xr16, (const float4*)att2,
        offsets, csr_src, (const float4*)bias2, (uint4*)hC2_16, N);

    // dueling heads
    head_kernel<<<B, 256, 0, stream>>>(hE16, hC1_16, hC2_16, indices,
                                       qw1, qb1, qw2, qb2, vw1, vb1, vw2, vb2,
                                       (float*)d_out);
}

// Round 5
// 285.538 us; speedup vs baseline: 1.4810x; 1.0992x over previous
//
#include <hip/hip_runtime.h>

#define IN_DIM 64
#define HID 64
#define HEADS 4
#define DD 256      // HID*HEADS
#define ENC_H 512
#define DUEL_H 128
#define NEG_SLOPE 0.2f

typedef _Float16 f16;
typedef __attribute__((ext_vector_type(2))) _Float16 f16x2;
typedef __attribute__((ext_vector_type(4))) _Float16 f16x4;
typedef __attribute__((ext_vector_type(8))) _Float16 f16x8;
typedef __attribute__((ext_vector_type(4))) float f32x4;

__device__ __forceinline__ f16x2 u2h(unsigned u) {
    union { unsigned u; f16x2 h; } c; c.u = u; return c.h;
}
__device__ __forceinline__ unsigned h2u(f16x2 h) {
    union { unsigned u; f16x2 h; } c; c.h = h; return c.u;
}

// ---------------- fused prep: cast x, transpose+cast weights, zero counts ----------------

__global__ void prep_all(
    const float4* __restrict__ x, f16x4* __restrict__ x16, int nx4,
    const float* __restrict__ w1, const float* __restrict__ w2,
    const float* __restrict__ wl1, const float* __restrict__ wr1,
    const float* __restrict__ wl2, const float* __restrict__ wr2,
    f16* __restrict__ w1t, f16* __restrict__ w2t,
    f16* __restrict__ wcat1, f16* __restrict__ wcat2,
    int* __restrict__ counts, int ncnt) {
    int i = blockIdx.x * blockDim.x + threadIdx.x;
    if (i < nx4) {
        float4 v = x[i];
        f16x4 o = {(f16)v.x, (f16)v.y, (f16)v.z, (f16)v.w};
        x16[i] = o;
        return;
    }
    i -= nx4;
    if (i < 229376) {
        if (i < 32768) {                       // w1 [64][512] -> w1t [512][64]
            int k = i >> 9, n = i & 511;
            w1t[n * 64 + k] = (f16)w1[i];
        } else if (i < 65536) {                // w2 [512][64] -> w2t [64][512]
            int j = i - 32768; int k = j >> 6, n = j & 63;
            w2t[n * 512 + k] = (f16)w2[j];
        } else if (i < 81920) {                // wl1 [64][256] -> wcat1[0..256)[64]
            int j = i - 65536; int k = j >> 8, n = j & 255;
            wcat1[n * 64 + k] = (f16)wl1[j];
        } else if (i < 98304) {                // wr1 -> wcat1[256..512)[64]
            int j = i - 81920; int k = j >> 8, n = j & 255;
            wcat1[(256 + n) * 64 + k] = (f16)wr1[j];
        } else if (i < 163840) {               // wl2 [256][256] -> wcat2[0..256)[256]
            int j = i - 98304; int k = j >> 8, n = j & 255;
            wcat2[n * 256 + k] = (f16)wl2[j];
        } else {                               // wr2 -> wcat2[256..512)[256]
            int j = i - 163840; int k = j >> 8, n = j & 255;
            wcat2[(256 + n) * 256 + k] = (f16)wr2[j];
        }
        return;
    }
    i -= 229376;
    if (i < ncnt) counts[i] = 0;
}

// ---------------- CSR build ----------------

__global__ void hist_kernel(const int* __restrict__ ei, int E, int N, int* counts) {
    int e = blockIdx.x * blockDim.x + threadIdx.x;
    int Etot = E + N;
    if (e >= Etot) return;
    int dst = (e < E) ? ei[E + e] : (e - E);
    atomicAdd(&counts[dst], 1);
}

// Tiled LDS-coalesced exclusive scan: counts[0..n) -> offsets/cursor, offsets[n]=total.
// One block, 1024 threads. Tiles of 8192 ints staged coalesced (int4) into LDS;
// each thread scans 8 contiguous elems; two-level shfl scan across block;
// coalesced int4 writes of the prefix values.

__global__ __launch_bounds__(1024) void scan_kernel(const int* __restrict__ counts,
                                                    int* offsets, int* cursor, int n) {
    constexpr int TILE = 8192;
    __shared__ int tile[TILE];
    __shared__ int wsum[16];
    const int t = threadIdx.x;
    const int lane = t & 63, wid = t >> 6;
    int running = 0;

    for (int base = 0; base < n; base += TILE) {
        const int cnt = (n - base < TILE) ? (n - base) : TILE;

        // coalesced int4 stage into LDS (cnt is always a multiple of 4 here;
        // generic tail handled scalar)
        int nv4 = cnt >> 2;
        for (int i = t; i < nv4; i += 1024)
            ((int4*)tile)[i] = ((const int4*)(counts + base))[i];
        for (int i = (nv4 << 2) + t; i < cnt; i += 1024)
            tile[i] = counts[base + i];
        __syncthreads();

        // per-thread serial sum of 8 contiguous elems
        int e0 = t * 8;
        int nj = cnt - e0; if (nj < 0) nj = 0; if (nj > 8) nj = 8;
        int v8[8];
        int s = 0;
#pragma unroll
        for (int j = 0; j < 8; ++j) {
            int val = (j < nj) ? tile[e0 + j] : 0;
            v8[j] = val; s += val;
        }

        // two-level inclusive scan of s across 1024 threads
        int v = s;
        for (int off = 1; off < 64; off <<= 1) {
            int u = __shfl_up(v, off);
            if (lane >= off) v += u;
        }
        if (lane == 63) wsum[wid] = v;
        __syncthreads();
        if (wid == 0) {
            int wv = (lane < 16) ? wsum[lane] : 0;
            for (int off = 1; off < 16; off <<= 1) {
                int u = __shfl_up(wv, off);
                if (lane >= off) wv += u;
            }
            if (lane < 16) wsum[lane] = wv;
        }
        __syncthreads();
        int excl = v - s + (wid > 0 ? wsum[wid - 1] : 0);

        // per-thread prefix values, coalesced int4 writes
        int run = running + excl;
        int o8[8];
#pragma unroll
        for (int j = 0; j < 8; ++j) { o8[j] = run; run += v8[j]; }
        if (nj == 8) {
            int4 a = make_int4(o8[0], o8[1], o8[2], o8[3]);
            int4 b = make_int4(o8[4], o8[5], o8[6], o8[7]);
            *(int4*)&offsets[base + e0]     = a;
            *(int4*)&offsets[base + e0 + 4] = b;
            *(int4*)&cursor[base + e0]      = a;
            *(int4*)&cursor[base + e0 + 4]  = b;
        } else {
            for (int j = 0; j < nj; ++j) {
                offsets[base + e0 + j] = o8[j];
                cursor[base + e0 + j]  = o8[j];
            }
        }
        running += wsum[15];
        __syncthreads();   // protect tile[]/wsum[] before next iteration
    }
    if (t == 0) offsets[n] = running;
}

__global__ void scatter_kernel(const int* __restrict__ ei, int E, int N,
                               int* cursor, int* csr_src) {
    int e = blockIdx.x * blockDim.x + threadIdx.x;
    int Etot = E + N;
    if (e >= Etot) return;
    int src, dst;
    if (e < E) { src = ei[e]; dst = ei[E + e]; }
    else       { src = e - E; dst = e - E; }
    int pos = atomicAdd(&cursor[dst], 1);
    csr_src[pos] = src;
}

// ---------------- B-slab-resident fp16 MFMA GEMM, BM=64 ----------------

template <int K, int BN>
__global__ __launch_bounds__(256) void gemm_slab(
    const f16* __restrict__ A, const f16* __restrict__ Bt,
    const float* __restrict__ biasA, const float* __restrict__ biasB, int NS,
    int M, int relu,
    f16* __restrict__ C1, f16* __restrict__ C2) {
    constexpr int KS = K / 32;
    constexpr int PF = (KS < 8) ? KS : 8;      // deeper A prefetch (8 in flight)
    constexpr int COLW = BN / 2;
    constexpr int NT = COLW / 16;
    constexpr int SB = K + 8;
    constexpr int CE = COLW + 8;
    constexpr int SLABSZ = BN * SB;
    constexpr int EPISZ = 4 * 32 * CE;
    constexpr int SMEMSZ = (SLABSZ > EPISZ ? SLABSZ : EPISZ);

    __shared__ __align__(16) f16 smem[SMEMSZ];
    f16* Bs = smem;

    int tid = threadIdx.x;
    int wave = tid >> 6, lane = tid & 63;
    int quad = lane >> 4, l16 = lane & 15;
    int wr = wave >> 1, wc = wave & 1;
    int row0 = blockIdx.y * 64;
    int col0 = blockIdx.x * BN;

    constexpr int NCH = BN * K / 8;
#pragma unroll
    for (int i = 0; i < NCH / 256; ++i) {
        int c = tid + i * 256;
        int r = c / (K / 8), ko = (c % (K / 8)) * 8;
        uint4 v = *(const uint4*)&Bt[(size_t)(col0 + r) * K + ko];
        *(uint4*)&Bs[r * SB + ko] = v;
    }
    __syncthreads();

    const f16* Aptr[2];
#pragma unroll
    for (int mt = 0; mt < 2; ++mt) {
        int arow = row0 + wr * 32 + mt * 16 + l16;
        if (arow >= M) arow = M - 1;
        Aptr[mt] = &A[(size_t)arow * K + quad * 8];
    }

    f32x4 acc[2][NT];
#pragma unroll
    for (int mt = 0; mt < 2; ++mt)
#pragma unroll
        for (int j = 0; j < NT; ++j) acc[mt][j] = (f32x4){0.f, 0.f, 0.f, 0.f};

    f16x8 afb[2][PF];
#pragma unroll
    for (int mt = 0; mt < 2; ++mt)
#pragma unroll
        for (int i = 0; i < PF; ++i)
            afb[mt][i] = *(const f16x8*)&Aptr[mt][i * 32];

#pragma unroll
    for (int s = 0; s < KS; ++s) {
        f16x8 af0 = afb[0][s % PF], af1 = afb[1][s % PF];
        if (s + PF < KS) {
            afb[0][s % PF] = *(const f16x8*)&Aptr[0][(s + PF) * 32];
            afb[1][s % PF] = *(const f16x8*)&Aptr[1][(s + PF) * 32];
        }
        const f16* bbase = &Bs[(size_t)(wc * COLW) * SB + s * 32 + quad * 8];
#pragma unroll
        for (int nt = 0; nt < NT; ++nt) {
            f16x8 bf = *(const f16x8*)&bbase[(nt * 16 + l16) * SB];
            acc[0][nt] = __builtin_amdgcn_mfma_f32_16x16x32_f16(af0, bf, acc[0][nt], 0, 0, 0);
            acc[1][nt] = __builtin_amdgcn_mfma_f32_16x16x32_f16(af1, bf, acc[1][nt], 0, 0, 0);
        }
    }

    __syncthreads();
    f16* ep = &smem[wave * 32 * CE];
#pragma unroll
    for (int mt = 0; mt < 2; ++mt)
#pragma unroll
        for (int nt = 0; nt < NT; ++nt) {
            int gcol = col0 + wc * COLW + nt * 16 + l16;
            float bb = (gcol < NS) ? biasA[gcol] : biasB[gcol - NS];
#pragma unroll
            for (int r = 0; r < 4; ++r) {
                float v = acc[mt][nt][r] + bb;
                if (relu) v = fmaxf(v, 0.f);
                ep[(mt * 16 + quad * 4 + r) * CE + nt * 16 + l16] = (f16)v;
            }
        }
    constexpr int CPR = COLW / 8;
    constexpr int NPASS = (32 * CPR) / 64;
#pragma unroll
    for (int i = 0; i < NPASS; ++i) {
        int u = lane + i * 64;
        int row = u / CPR, seg = u % CPR;
        uint4 v = *(const uint4*)&ep[row * CE + seg * 8];
        int grow = row0 + wr * 32 + row;
        int gcol = col0 + wc * COLW + seg * 8;
        if (grow < M) {
            if (gcol < NS) *(uint4*)&C1[(size_t)grow * NS + gcol] = v;
            else           *(uint4*)&C2[(size_t)grow * NS + (gcol - NS)] = v;
        }
    }
}

// ---------------- fused GATv2: 1 node/wave, half-wave edge parity ----------------
// 32 lanes per half, each lane 8 dims (uint4); halves take alternating edges
// of the SAME node (no degree divergence). Head = 8-lane group; leaky fused
// into dot: att.leaky(t) = (.6 att).t + (.4 att).|t|. Cross-half combine via
// shfl_xor(32) at the end.

__global__ __launch_bounds__(256) void gat_fused_kernel(
    const uint4* __restrict__ xl, const uint4* __restrict__ xr,
    const float4* __restrict__ att,
    const int* __restrict__ offsets, const int* __restrict__ csr_src,
    const float4* __restrict__ bias, uint4* __restrict__ h16, int N) {
    int node = (blockIdx.x * blockDim.x + threadIdx.x) >> 6;
    int lane = threadIdx.x & 63;
    int half = lane >> 5, l32 = lane & 31;
    if (node >= N) return;
    int s = offsets[node], e = offsets[node + 1];
    uint4 xrw = xr[(size_t)node * 32 + l32];
    f16x2 xr0 = u2h(xrw.x), xr1 = u2h(xrw.y), xr2 = u2h(xrw.z), xr3 = u2h(xrw.w);
    float4 awA = att[l32 * 2], awB = att[l32 * 2 + 1];
    f16x2 a6[4] = {{(f16)(0.6f * awA.x), (f16)(0.6f * awA.y)},
                   {(f16)(0.6f * awA.z), (f16)(0.6f * awA.w)},
                   {(f16)(0.6f * awB.x), (f16)(0.6f * awB.y)},
                   {(f16)(0.6f * awB.z), (f16)(0.6f * awB.w)}};
    f16x2 a4[4] = {{(f16)(0.4f * awA.x), (f16)(0.4f * awA.y)},
                   {(f16)(0.4f * awA.z), (f16)(0.4f * awA.w)},
                   {(f16)(0.4f * awB.x), (f16)(0.4f * awB.y)},
                   {(f16)(0.4f * awB.z), (f16)(0.4f * awB.w)}};
    float denom = 0.f;
    float acc0 = 0.f, acc1 = 0.f, acc2 = 0.f, acc3 = 0.f;
    float acc4 = 0.f, acc5 = 0.f, acc6 = 0.f, acc7 = 0.f;

    auto edge_dot = [&](uint4 raw) -> float {
        f16x2 t0 = u2h(raw.x) + xr0, t1 = u2h(raw.y) + xr1;
        f16x2 t2 = u2h(raw.z) + xr2, t3 = u2h(raw.w) + xr3;
        float d = __builtin_amdgcn_fdot2(t0, a6[0], 0.f, false);
        d = __builtin_amdgcn_fdot2(u2h(h2u(t0) & 0x7FFF7FFFu), a4[0], d, false);
        d = __builtin_amdgcn_fdot2(t1, a6[1], d, false);
        d = __builtin_amdgcn_fdot2(u2h(h2u(t1) & 0x7FFF7FFFu), a4[1], d, false);
        d = __builtin_amdgcn_fdot2(t2, a6[2], d, false);
        d = __builtin_amdgcn_fdot2(u2h(h2u(t2) & 0x7FFF7FFFu), a4[2], d, false);
        d = __builtin_amdgcn_fdot2(t3, a6[3], d, false);
        d = __builtin_amdgcn_fdot2(u2h(h2u(t3) & 0x7FFF7FFFu), a4[3], d, false);
        return d;
    };
    auto accum = [&](uint4 raw, float ee) {
        f16x2 v0 = u2h(raw.x), v1 = u2h(raw.y), v2 = u2h(raw.z), v3 = u2h(raw.w);
        acc0 = fmaf(ee, (float)v0.x, acc0); acc1 = fmaf(ee, (float)v0.y, acc1);
        acc2 = fmaf(ee, (float)v1.x, acc2); acc3 = fmaf(ee, (float)v1.y, acc3);
        acc4 = fmaf(ee, (float)v2.x, acc4); acc5 = fmaf(ee, (float)v2.y, acc5);
        acc6 = fmaf(ee, (float)v3.x, acc6); acc7 = fmaf(ee, (float)v3.y, acc7);
    };

    int p = s + half;   // this half's first edge; halves interleave stride 2
    for (; p + 6 < e; p += 8) {
        uint4 raw[4];
#pragma unroll
        for (int j = 0; j < 4; ++j)
            raw[j] = xl[(size_t)csr_src[p + j * 2] * 32 + l32];
        float sc[4];
#pragma unroll
        for (int j = 0; j < 4; ++j) sc[j] = edge_dot(raw[j]);
#pragma unroll
        for (int j = 0; j < 4; ++j) sc[j] += __shfl_xor(sc[j], 1);
#pragma unroll
        for (int j = 0; j < 4; ++j) sc[j] += __shfl_xor(sc[j], 2);
#pragma unroll
        for (int j = 0; j < 4; ++j) sc[j] += __shfl_xor(sc[j], 4);
#pragma unroll
        for (int j = 0; j < 4; ++j) {
            float ee = __expf(sc[j]);
            denom += ee;
            accum(raw[j], ee);
        }
    }
    for (; p < e; p += 2) {
        uint4 raw = xl[(size_t)csr_src[p] * 32 + l32];
        float d = edge_dot(raw);
        d += __shfl_xor(d, 1);
        d += __shfl_xor(d, 2);
        d += __shfl_xor(d, 4);
        float ee = __expf(d);
        denom += ee;
        accum(raw, ee);
    }
    // combine halves
    denom += __shfl_xor(denom, 32);
    acc0 += __shfl_xor(acc0, 32); acc1 += __shfl_xor(acc1, 32);
    acc2 += __shfl_xor(acc2, 32); acc3 += __shfl_xor(acc3, 32);
    acc4 += __shfl_xor(acc4, 32); acc5 += __shfl_xor(acc5, 32);
    acc6 += __shfl_xor(acc6, 32); acc7 += __shfl_xor(acc7, 32);

    if (half == 0) {
        float inv = 1.f / (denom + 1e-16f);
        float4 bbA = bias[l32 * 2], bbB = bias[l32 * 2 + 1];
        float o0 = fmaxf(fmaf(acc0, inv, bbA.x), 0.f);
        float o1 = fmaxf(fmaf(acc1, inv, bbA.y), 0.f);
        float o2 = fmaxf(fmaf(acc2, inv, bbA.z), 0.f);
        float o3 = fmaxf(fmaf(acc3, inv, bbA.w), 0.f);
        float o4 = fmaxf(fmaf(acc4, inv, bbB.x), 0.f);
        float o5 = fmaxf(fmaf(acc5, inv, bbB.y), 0.f);
        float o6 = fmaxf(fmaf(acc6, inv, bbB.z), 0.f);
        float o7 = fmaxf(fmaf(acc7, inv, bbB.w), 0.f);
        f16x2 h0 = {(f16)o0, (f16)o1}, h1 = {(f16)o2, (f16)o3};
        f16x2 h2 = {(f16)o4, (f16)o5}, h3 = {(f16)o6, (f16)o7};
        uint4 outw = make_uint4(h2u(h0), h2u(h1), h2u(h2), h2u(h3));
        h16[(size_t)node * 32 + l32] = outw;
    }
}

// ---------------- dueling heads (f16 feature tables) ----------------

__global__ __launch_bounds__(256) void head_kernel(
    const f16* __restrict__ hE16, const f16* __restrict__ hC1_16,
    const f16* __restrict__ hC2_16, const int* __restrict__ indices,
    const float* __restrict__ qw1, const float* __restrict__ qb1,
    const float* __restrict__ qw2, const float* __restrict__ qb2,
    const float* __restrict__ vw1, const float* __restrict__ vb1,
    const float* __restrict__ vw2, const float* __restrict__ vb2,
    float* __restrict__ out) {
    __shared__ float feat[576];
    __shared__ float red[384];
    int b = blockIdx.x;
    int t = threadIdx.x;
    int node = indices[b];
    for (int i = t; i < 576; i += 256) {
        float f;
        if (i < 64) f = (float)hE16[(size_t)node * 64 + i];
        else if (i < 320) f = (float)hC1_16[(size_t)node * 256 + i - 64];
        else f = (float)hC2_16[(size_t)node * 256 + i - 320];
        feat[i] = f;
    }
    __syncthreads();
    if (t < 128) {
        float aq = qb1[t];
        for (int k = 0; k < 576; ++k)
            aq = fmaf(feat[k], qw1[k * 128 + t], aq);
        aq = fmaxf(aq, 0.f);
        red[t]       = aq * qw2[t * 2 + 0];
        red[128 + t] = aq * qw2[t * 2 + 1];
    } else {
        int tv = t - 128;
        float av = vb1[tv];
        for (int k = 0; k < 576; ++k)
            av = fmaf(feat[k], vw1[k * 128 + tv], av);
        av = fmaxf(av, 0.f);
        red[256 + tv] = av * vw2[tv];
    }
    __syncthreads();
    for (int s = 64; s > 0; s >>= 1) {
        if (t < s) {
            red[t] += red[t + s];
            red[128 + t] += red[128 + t + s];
            red[256 + t] += red[256 + t + s];
        }
        __syncthreads();
    }
    if (t == 0) {
        float q0 = red[0] + qb2[0];
        float q1 = red[128] + qb2[1];
        float v  = red[256] + vb2[0];
        float mean = 0.5f * (q0 + q1);
        out[b * 2 + 0] = q0 - mean + v;
        out[b * 2 + 1] = q1 - mean + v;
    }
}

// ---------------- launch ----------------

extern "C" void kernel_launch(void* const* d_in, const int* in_sizes, int n_in,
                              void* d_out, int out_size, void* d_ws, size_t ws_size,
                              hipStream_t stream) {
    const float* x      = (const float*)d_in[0];
    const int*   ei     = (const int*)d_in[1];
    const int*   indices= (const int*)d_in[2];
    const float* enc_w1 = (const float*)d_in[3];
    const float* enc_b1 = (const float*)d_in[4];
    const float* enc_w2 = (const float*)d_in[5];
    const float* enc_b2 = (const float*)d_in[6];
    const float* wl1    = (const float*)d_in[7];
    const float* bl1    = (const float*)d_in[8];
    const float* wr1    = (const float*)d_in[9];
    const float* br1    = (const float*)d_in[10];
    const float* att1   = (const float*)d_in[11];
    const float* bias1  = (const float*)d_in[12];
    const float* wl2    = (const float*)d_in[13];
    const float* bl2    = (const float*)d_in[14];
    const float* wr2    = (const float*)d_in[15];
    const float* br2    = (const float*)d_in[16];
    const float* att2   = (const float*)d_in[17];
    const float* bias2  = (const float*)d_in[18];
    const float* qw1    = (const float*)d_in[19];
    const float* qb1    = (const float*)d_in[20];
    const float* qw2    = (const float*)d_in[21];
    const float* qb2    = (const float*)d_in[22];
    const float* vw1    = (const float*)d_in[23];
    const float* vb1    = (const float*)d_in[24];
    const float* vw2    = (const float*)d_in[25];
    const float* vb2    = (const float*)d_in[26];

    const int N = in_sizes[0] / IN_DIM;
    const int E = in_sizes[1] / 2;
    const int B = in_sizes[2];
    const int Etot = E + N;

    // ---- workspace arena ----
    char* wsb = (char*)d_ws;
    size_t off = 0;
    auto alloc = [&](size_t bytes) -> void* {
        void* p = wsb + off;
        off = (off + bytes + 255) & ~(size_t)255;
        return p;
    };
    f16* x16     = (f16*)alloc((size_t)N * 64 * 2);
    f16* h1_16   = (f16*)alloc((size_t)N * 512 * 2);
    f16* hE16    = (f16*)alloc((size_t)N * 64 * 2);
    f16* xl16    = (f16*)alloc((size_t)N * 256 * 2);
    f16* xr16    = (f16*)alloc((size_t)N * 256 * 2);
    f16* hC1_16  = (f16*)alloc((size_t)N * 256 * 2);
    f16* hC2_16  = (f16*)alloc((size_t)N * 256 * 2);
    f16* w1t     = (f16*)alloc((size_t)ENC_H * IN_DIM * 2);
    f16* w2t     = (f16*)alloc((size_t)HID * ENC_H * 2);
    f16* wcat1   = (f16*)alloc((size_t)512 * HID * 2);
    f16* wcat2   = (f16*)alloc((size_t)512 * DD * 2);
    int* counts  = (int*)alloc((size_t)(N + 1) * 4);
    int* offsets = (int*)alloc((size_t)(N + 1) * 4);
    int* cursor  = (int*)alloc((size_t)(N + 1) * 4);
    int* csr_src = (int*)alloc((size_t)Etot * 4);

    // ---- prep ----
    int nx4 = N * 16;
    int ntot = nx4 + 229376 + (N + 1);
    prep_all<<<(ntot + 255) / 256, 256, 0, stream>>>(
        (const float4*)x, (f16x4*)x16, nx4,
        enc_w1, enc_w2, wl1, wr1, wl2, wr2,
        w1t, w2t, wcat1, wcat2, counts, N + 1);

    // ---- CSR by dst ----
    hist_kernel<<<(Etot + 255) / 256, 256, 0, stream>>>(ei, E, N, counts);
    scan_kernel<<<1, 1024, 0, stream>>>(counts, offsets, cursor, N);
    scatter_kernel<<<(Etot + 255) / 256, 256, 0, stream>>>(ei, E, N, cursor, csr_src);

    dim3 blk(256);
    int grows = (N + 63) / 64;   // 313

    // encoder
    gemm_slab<64, 128><<<dim3(4, grows), blk, 0, stream>>>(
        x16, w1t, enc_b1, enc_b1, 512, N, 1, h1_16, h1_16);
    gemm_slab<512, 64><<<dim3(1, grows), blk, 0, stream>>>(
        h1_16, w2t, enc_b2, enc_b2, 64, N, 1, hE16, hE16);

    // conv1 transform + GAT
    gemm_slab<64, 128><<<dim3(4, grows), blk, 0, stream>>>(
        hE16, wcat1, bl1, br1, DD, N, 0, xl16, xr16);
    int gatg = (N * 64 + 255) / 256;
    gat_fused_kernel<<<gatg, 256, 0, stream>>>(
        (const uint4*)xl16, (const uint4*)xr16, (const float4*)att1,
        offsets, csr_src, (const float4*)bias1, (uint4*)hC1_16, N);

    // conv2 transform + GAT
    gemm_slab<256, 128><<<dim3(4, grows), blk, 0, stream>>>(
        hC1_16, wcat2, bl2, br2, DD, N, 0, xl16, xr16);
    gat_fused_kernel<<<gatg, 256, 0, stream>>>(
        (const uint4*)xl16, (const uint4*)xr16, (const float4*)att2,
        offsets, csr_src, (const float4*)bias2, (uint4*)hC2_16, N);

    // dueling heads
    head_kernel<<<B, 256, 0, stream>>>(hE16, hC1_16, hC2_16, indices,
                                       qw1, qb1, qw2, qb2, vw1, vb1, vw2, vb2,
                                       (float*)d_out);
}

// Round 6
// 265.741 us; speedup vs baseline: 1.5913x; 1.0745x over previous
//
#include <hip/hip_runtime.h>

#define IN_DIM 64
#define HID 64
#define HEADS 4
#define DD 256      // HID*HEADS
#define ENC_H 512
#define DUEL_H 128
#define NEG_SLOPE 0.2f

typedef _Float16 f16;
typedef __attribute__((ext_vector_type(2))) _Float16 f16x2;
typedef __attribute__((ext_vector_type(4))) _Float16 f16x4;
typedef __attribute__((ext_vector_type(8))) _Float16 f16x8;
typedef __attribute__((ext_vector_type(4))) float f32x4;

__device__ __forceinline__ f16x2 u2h(unsigned u) {
    union { unsigned u; f16x2 h; } c; c.u = u; return c.h;
}
__device__ __forceinline__ unsigned h2u(f16x2 h) {
    union { unsigned u; f16x2 h; } c; c.h = h; return c.u;
}

// ---------------- fused prep: cast x, transpose+cast weights, zero counts ----------------

__global__ void prep_all(
    const float4* __restrict__ x, f16x4* __restrict__ x16, int nx4,
    const float* __restrict__ w1, const float* __restrict__ w2,
    const float* __restrict__ wl1, const float* __restrict__ wr1,
    const float* __restrict__ wl2, const float* __restrict__ wr2,
    f16* __restrict__ w1t, f16* __restrict__ w2t,
    f16* __restrict__ wcat1, f16* __restrict__ wcat2,
    int* __restrict__ counts, int ncnt) {
    int i = blockIdx.x * blockDim.x + threadIdx.x;
    if (i < nx4) {
        float4 v = x[i];
        f16x4 o = {(f16)v.x, (f16)v.y, (f16)v.z, (f16)v.w};
        x16[i] = o;
        return;
    }
    i -= nx4;
    if (i < 229376) {
        if (i < 32768) {                       // w1 [64][512] -> w1t [512][64]
            int k = i >> 9, n = i & 511;
            w1t[n * 64 + k] = (f16)w1[i];
        } else if (i < 65536) {                // w2 [512][64] -> w2t [64][512]
            int j = i - 32768; int k = j >> 6, n = j & 63;
            w2t[n * 512 + k] = (f16)w2[j];
        } else if (i < 81920) {                // wl1 [64][256] -> wcat1[0..256)[64]
            int j = i - 65536; int k = j >> 8, n = j & 255;
            wcat1[n * 64 + k] = (f16)wl1[j];
        } else if (i < 98304) {                // wr1 -> wcat1[256..512)[64]
            int j = i - 81920; int k = j >> 8, n = j & 255;
            wcat1[(256 + n) * 64 + k] = (f16)wr1[j];
        } else if (i < 163840) {               // wl2 [256][256] -> wcat2[0..256)[256]
            int j = i - 98304; int k = j >> 8, n = j & 255;
            wcat2[n * 256 + k] = (f16)wl2[j];
        } else {                               // wr2 -> wcat2[256..512)[256]
            int j = i - 163840; int k = j >> 8, n = j & 255;
            wcat2[(256 + n) * 256 + k] = (f16)wr2[j];
        }
        return;
    }
    i -= 229376;
    if (i < ncnt) counts[i] = 0;
}

// ---------------- GEMM body (B-slab-resident fp16 MFMA, BM=64) ----------------

template <int K, int BN>
struct GemmCfg {
    static constexpr int SB = K + 8;
    static constexpr int CE = BN / 2 + 8;
    static constexpr int SLABSZ = BN * SB;
    static constexpr int EPISZ = 4 * 32 * CE;
    static constexpr int SMEMSZ = SLABSZ > EPISZ ? SLABSZ : EPISZ;   // in f16
};

template <int K, int BN>
__device__ __forceinline__ void gemm_body(
    int bx, int by, f16* __restrict__ smem,
    const f16* __restrict__ A, const f16* __restrict__ Bt,
    const float* __restrict__ biasA, const float* __restrict__ biasB, int NS,
    int M, int relu,
    f16* __restrict__ C1, f16* __restrict__ C2) {
    constexpr int KS = K / 32;
    constexpr int PF = (KS < 8) ? KS : 8;
    constexpr int COLW = BN / 2;
    constexpr int NT = COLW / 16;
    constexpr int SB = GemmCfg<K, BN>::SB;
    constexpr int CE = GemmCfg<K, BN>::CE;

    f16* Bs = smem;
    int tid = threadIdx.x;
    int wave = tid >> 6, lane = tid & 63;
    int quad = lane >> 4, l16 = lane & 15;
    int wr = wave >> 1, wc = wave & 1;
    int row0 = by * 64;
    int col0 = bx * BN;

    constexpr int NCH = BN * K / 8;
#pragma unroll
    for (int i = 0; i < NCH / 256; ++i) {
        int c = tid + i * 256;
        int r = c / (K / 8), ko = (c % (K / 8)) * 8;
        uint4 v = *(const uint4*)&Bt[(size_t)(col0 + r) * K + ko];
        *(uint4*)&Bs[r * SB + ko] = v;
    }
    __syncthreads();

    const f16* Aptr[2];
#pragma unroll
    for (int mt = 0; mt < 2; ++mt) {
        int arow = row0 + wr * 32 + mt * 16 + l16;
        if (arow >= M) arow = M - 1;
        Aptr[mt] = &A[(size_t)arow * K + quad * 8];
    }

    f32x4 acc[2][NT];
#pragma unroll
    for (int mt = 0; mt < 2; ++mt)
#pragma unroll
        for (int j = 0; j < NT; ++j) acc[mt][j] = (f32x4){0.f, 0.f, 0.f, 0.f};

    f16x8 afb[2][PF];
#pragma unroll
    for (int mt = 0; mt < 2; ++mt)
#pragma unroll
        for (int i = 0; i < PF; ++i)
            afb[mt][i] = *(const f16x8*)&Aptr[mt][i * 32];

#pragma unroll
    for (int s = 0; s < KS; ++s) {
        f16x8 af0 = afb[0][s % PF], af1 = afb[1][s % PF];
        if (s + PF < KS) {
            afb[0][s % PF] = *(const f16x8*)&Aptr[0][(s + PF) * 32];
            afb[1][s % PF] = *(const f16x8*)&Aptr[1][(s + PF) * 32];
        }
        const f16* bbase = &Bs[(size_t)(wc * COLW) * SB + s * 32 + quad * 8];
#pragma unroll
        for (int nt = 0; nt < NT; ++nt) {
            f16x8 bf = *(const f16x8*)&bbase[(nt * 16 + l16) * SB];
            acc[0][nt] = __builtin_amdgcn_mfma_f32_16x16x32_f16(af0, bf, acc[0][nt], 0, 0, 0);
            acc[1][nt] = __builtin_amdgcn_mfma_f32_16x16x32_f16(af1, bf, acc[1][nt], 0, 0, 0);
        }
    }

    __syncthreads();
    f16* ep = &smem[wave * 32 * CE];
#pragma unroll
    for (int mt = 0; mt < 2; ++mt)
#pragma unroll
        for (int nt = 0; nt < NT; ++nt) {
            int gcol = col0 + wc * COLW + nt * 16 + l16;
            float bb = (gcol < NS) ? biasA[gcol] : biasB[gcol - NS];
#pragma unroll
            for (int r = 0; r < 4; ++r) {
                float v = acc[mt][nt][r] + bb;
                if (relu) v = fmaxf(v, 0.f);
                ep[(mt * 16 + quad * 4 + r) * CE + nt * 16 + l16] = (f16)v;
            }
        }
    constexpr int CPR = COLW / 8;
    constexpr int NPASS = (32 * CPR) / 64;
#pragma unroll
    for (int i = 0; i < NPASS; ++i) {
        int u = lane + i * 64;
        int row = u / CPR, seg = u % CPR;
        uint4 v = *(const uint4*)&ep[row * CE + seg * 8];
        int grow = row0 + wr * 32 + row;
        int gcol = col0 + wc * COLW + seg * 8;
        if (grow < M) {
            if (gcol < NS) *(uint4*)&C1[(size_t)grow * NS + gcol] = v;
            else           *(uint4*)&C2[(size_t)grow * NS + (gcol - NS)] = v;
        }
    }
}

template <int K, int BN>
__global__ __launch_bounds__(256) void gemm_slab(
    const f16* __restrict__ A, const f16* __restrict__ Bt,
    const float* __restrict__ biasA, const float* __restrict__ biasB, int NS,
    int M, int relu,
    f16* __restrict__ C1, f16* __restrict__ C2) {
    __shared__ __align__(16) f16 smem[GemmCfg<K, BN>::SMEMSZ];
    gemm_body<K, BN>(blockIdx.x, blockIdx.y, smem, A, Bt, biasA, biasB, NS, M, relu, C1, C2);
}

// ---------------- aux bodies: hist / scan / scatter ----------------

__device__ __forceinline__ void hist_body(int auxbid, const int* __restrict__ ei,
                                          int E, int N, int* __restrict__ counts) {
    int e = auxbid * 256 + threadIdx.x;
    int Etot = E + N;
    if (e >= Etot) return;
    int dst = (e < E) ? ei[E + e] : (e - E);
    atomicAdd(&counts[dst], 1);
}

__device__ __forceinline__ void scatter_body(int auxbid, const int* __restrict__ ei,
                                             int E, int N, int* __restrict__ cursor,
                                             int* __restrict__ csr_src) {
    int e = auxbid * 256 + threadIdx.x;
    int Etot = E + N;
    if (e >= Etot) return;
    int src, dst;
    if (e < E) { src = ei[e]; dst = ei[E + e]; }
    else       { src = e - E; dst = e - E; }
    int pos = atomicAdd(&cursor[dst], 1);
    csr_src[pos] = src;
}

// Tiled LDS-coalesced exclusive scan, 256 threads, one block. tile = 2048 ints.
__device__ void scan_body(int* __restrict__ tile, const int* __restrict__ counts,
                          int* __restrict__ offsets, int* __restrict__ cursor, int n) {
    __shared__ int wsum[4];
    const int t = threadIdx.x;
    const int lane = t & 63, wid = t >> 6;
    int running = 0;
    for (int base = 0; base < n; base += 2048) {
        const int cnt = (n - base < 2048) ? (n - base) : 2048;
        int nv4 = cnt >> 2;
        for (int i = t; i < nv4; i += 256)
            ((int4*)tile)[i] = ((const int4*)(counts + base))[i];
        for (int i = (nv4 << 2) + t; i < cnt; i += 256)
            tile[i] = counts[base + i];
        __syncthreads();

        int e0 = t * 8;
        int nj = cnt - e0; if (nj < 0) nj = 0; if (nj > 8) nj = 8;
        int v8[8];
        int s = 0;
#pragma unroll
        for (int j = 0; j < 8; ++j) {
            int val = (j < nj) ? tile[e0 + j] : 0;
            v8[j] = val; s += val;
        }
        int v = s;
        for (int off = 1; off < 64; off <<= 1) {
            int u = __shfl_up(v, off);
            if (lane >= off) v += u;
        }
        if (lane == 63) wsum[wid] = v;
        __syncthreads();
        int wadd = 0, tot = 0;
#pragma unroll
        for (int w = 0; w < 4; ++w) {
            int ws = wsum[w];
            if (w < wid) wadd += ws;
            tot += ws;
        }
        int excl = v - s + wadd;
        int run = running + excl;
        int o8[8];
#pragma unroll
        for (int j = 0; j < 8; ++j) { o8[j] = run; run += v8[j]; }
        if (nj == 8) {
            int4 a = make_int4(o8[0], o8[1], o8[2], o8[3]);
            int4 b = make_int4(o8[4], o8[5], o8[6], o8[7]);
            *(int4*)&offsets[base + e0]     = a;
            *(int4*)&offsets[base + e0 + 4] = b;
            *(int4*)&cursor[base + e0]      = a;
            *(int4*)&cursor[base + e0 + 4]  = b;
        } else {
            for (int j = 0; j < nj; ++j) {
                offsets[base + e0 + j] = o8[j];
                cursor[base + e0 + j]  = o8[j];
            }
        }
        running += tot;
        __syncthreads();   // protect tile/wsum before next iteration
    }
    if (t == 0) offsets[n] = running;
}

// ---------------- merged dispatches (independent work co-scheduled) ----------------
// enc1 + hist: both depend only on prep_all.
__global__ __launch_bounds__(256) void enc1_hist_kernel(
    const f16* __restrict__ A, const f16* __restrict__ Bt,
    const float* __restrict__ bias, int M, f16* __restrict__ C, int gemmBlocks,
    const int* __restrict__ ei, int E, int N, int* __restrict__ counts) {
    __shared__ __align__(16) f16 smem[GemmCfg<64, 128>::SMEMSZ];
    int bid = blockIdx.x;
    if (bid < gemmBlocks)
        gemm_body<64, 128>(bid & 3, bid >> 2, smem, A, Bt, bias, bias, 512, M, 1, C, C);
    else
        hist_body(bid - gemmBlocks, ei, E, N, counts);
}

// enc2 + scan: enc2 needs enc1 (prev dispatch); scan needs hist (prev dispatch).
__global__ __launch_bounds__(256) void enc2_scan_kernel(
    const f16* __restrict__ A, const f16* __restrict__ Bt,
    const float* __restrict__ bias, int M, f16* __restrict__ C, int gemmBlocks,
    const int* __restrict__ counts, int* __restrict__ offsets,
    int* __restrict__ cursor, int n) {
    constexpr int GB = GemmCfg<512, 64>::SMEMSZ * 2;
    constexpr int SB = 2048 * 4;
    constexpr int PB = GB > SB ? GB : SB;
    __shared__ __align__(16) char pool[PB];
    int bid = blockIdx.x;
    if (bid < gemmBlocks)
        gemm_body<512, 64>(0, bid, (f16*)pool, A, Bt, bias, bias, 64, M, 1, C, C);
    else
        scan_body((int*)pool, counts, offsets, cursor, n);
}

// conv1t + scatter: conv1t needs enc2; scatter needs scan.
__global__ __launch_bounds__(256) void conv1t_scatter_kernel(
    const f16* __restrict__ A, const f16* __restrict__ Bt,
    const float* __restrict__ biasA, const float* __restrict__ biasB, int M,
    f16* __restrict__ C1, f16* __restrict__ C2, int gemmBlocks,
    const int* __restrict__ ei, int E, int N,
    int* __restrict__ cursor, int* __restrict__ csr_src) {
    __shared__ __align__(16) f16 smem[GemmCfg<64, 128>::SMEMSZ];
    int bid = blockIdx.x;
    if (bid < gemmBlocks)
        gemm_body<64, 128>(bid & 3, bid >> 2, smem, A, Bt, biasA, biasB, DD, M, 0, C1, C2);
    else
        scatter_body(bid - gemmBlocks, ei, E, N, cursor, csr_src);
}

// ---------------- fused GATv2: 1 node/wave, half-wave edge parity ----------------

__global__ __launch_bounds__(256) void gat_fused_kernel(
    const uint4* __restrict__ xl, const uint4* __restrict__ xr,
    const float4* __restrict__ att,
    const int* __restrict__ offsets, const int* __restrict__ csr_src,
    const float4* __restrict__ bias, uint4* __restrict__ h16, int N) {
    int node = (blockIdx.x * blockDim.x + threadIdx.x) >> 6;
    int lane = threadIdx.x & 63;
    int half = lane >> 5, l32 = lane & 31;
    if (node >= N) return;
    int s = offsets[node], e = offsets[node + 1];
    uint4 xrw = xr[(size_t)node * 32 + l32];
    f16x2 xr0 = u2h(xrw.x), xr1 = u2h(xrw.y), xr2 = u2h(xrw.z), xr3 = u2h(xrw.w);
    float4 awA = att[l32 * 2], awB = att[l32 * 2 + 1];
    f16x2 a6[4] = {{(f16)(0.6f * awA.x), (f16)(0.6f * awA.y)},
                   {(f16)(0.6f * awA.z), (f16)(0.6f * awA.w)},
                   {(f16)(0.6f * awB.x), (f16)(0.6f * awB.y)},
                   {(f16)(0.6f * awB.z), (f16)(0.6f * awB.w)}};
    f16x2 a4[4] = {{(f16)(0.4f * awA.x), (f16)(0.4f * awA.y)},
                   {(f16)(0.4f * awA.z), (f16)(0.4f * awA.w)},
                   {(f16)(0.4f * awB.x), (f16)(0.4f * awB.y)},
                   {(f16)(0.4f * awB.z), (f16)(0.4f * awB.w)}};
    float denom = 0.f;
    float acc0 = 0.f, acc1 = 0.f, acc2 = 0.f, acc3 = 0.f;
    float acc4 = 0.f, acc5 = 0.f, acc6 = 0.f, acc7 = 0.f;

    auto edge_dot = [&](uint4 raw) -> float {
        f16x2 t0 = u2h(raw.x) + xr0, t1 = u2h(raw.y) + xr1;
        f16x2 t2 = u2h(raw.z) + xr2, t3 = u2h(raw.w) + xr3;
        float d = __builtin_amdgcn_fdot2(t0, a6[0], 0.f, false);
        d = __builtin_amdgcn_fdot2(u2h(h2u(t0) & 0x7FFF7FFFu), a4[0], d, false);
        d = __builtin_amdgcn_fdot2(t1, a6[1], d, false);
        d = __builtin_amdgcn_fdot2(u2h(h2u(t1) & 0x7FFF7FFFu), a4[1], d, false);
        d = __builtin_amdgcn_fdot2(t2, a6[2], d, false);
        d = __builtin_amdgcn_fdot2(u2h(h2u(t2) & 0x7FFF7FFFu), a4[2], d, false);
        d = __builtin_amdgcn_fdot2(t3, a6[3], d, false);
        d = __builtin_amdgcn_fdot2(u2h(h2u(t3) & 0x7FFF7FFFu), a4[3], d, false);
        return d;
    };
    auto accum = [&](uint4 raw, float ee) {
        f16x2 v0 = u2h(raw.x), v1 = u2h(raw.y), v2 = u2h(raw.z), v3 = u2h(raw.w);
        acc0 = fmaf(ee, (float)v0.x, acc0); acc1 = fmaf(ee, (float)v0.y, acc1);
        acc2 = fmaf(ee, (float)v1.x, acc2); acc3 = fmaf(ee, (float)v1.y, acc3);
        acc4 = fmaf(ee, (float)v2.x, acc4); acc5 = fmaf(ee, (float)v2.y, acc5);
        acc6 = fmaf(ee, (float)v3.x, acc6); acc7 = fmaf(ee, (float)v3.y, acc7);
    };

    int p = s + half;   // this half's first edge; halves interleave stride 2
    for (; p + 6 < e; p += 8) {
        uint4 raw[4];
#pragma unroll
        for (int j = 0; j < 4; ++j)
            raw[j] = xl[(size_t)csr_src[p + j * 2] * 32 + l32];
        float sc[4];
#pragma unroll
        for (int j = 0; j < 4; ++j) sc[j] = edge_dot(raw[j]);
#pragma unroll
        for (int j = 0; j < 4; ++j) sc[j] += __shfl_xor(sc[j], 1);
#pragma unroll
        for (int j = 0; j < 4; ++j) sc[j] += __shfl_xor(sc[j], 2);
#pragma unroll
        for (int j = 0; j < 4; ++j) sc[j] += __shfl_xor(sc[j], 4);
#pragma unroll
        for (int j = 0; j < 4; ++j) {
            float ee = __expf(sc[j]);
            denom += ee;
            accum(raw[j], ee);
        }
    }
    for (; p < e; p += 2) {
        uint4 raw = xl[(size_t)csr_src[p] * 32 + l32];
        float d = edge_dot(raw);
        d += __shfl_xor(d, 1);
        d += __shfl_xor(d, 2);
        d += __shfl_xor(d, 4);
        float ee = __expf(d);
        denom += ee;
        accum(raw, ee);
    }
    // combine halves
    denom += __shfl_xor(denom, 32);
    acc0 += __shfl_xor(acc0, 32); acc1 += __shfl_xor(acc1, 32);
    acc2 += __shfl_xor(acc2, 32); acc3 += __shfl_xor(acc3, 32);
    acc4 += __shfl_xor(acc4, 32); acc5 += __shfl_xor(acc5, 32);
    acc6 += __shfl_xor(acc6, 32); acc7 += __shfl_xor(acc7, 32);

    if (half == 0) {
        float inv = 1.f / (denom + 1e-16f);
        float4 bbA = bias[l32 * 2], bbB = bias[l32 * 2 + 1];
        float o0 = fmaxf(fmaf(acc0, inv, bbA.x), 0.f);
        float o1 = fmaxf(fmaf(acc1, inv, bbA.y), 0.f);
        float o2 = fmaxf(fmaf(acc2, inv, bbA.z), 0.f);
        float o3 = fmaxf(fmaf(acc3, inv, bbA.w), 0.f);
        float o4 = fmaxf(fmaf(acc4, inv, bbB.x), 0.f);
        float o5 = fmaxf(fmaf(acc5, inv, bbB.y), 0.f);
        float o6 = fmaxf(fmaf(acc6, inv, bbB.z), 0.f);
        float o7 = fmaxf(fmaf(acc7, inv, bbB.w), 0.f);
        f16x2 h0 = {(f16)o0, (f16)o1}, h1 = {(f16)o2, (f16)o3};
        f16x2 h2 = {(f16)o4, (f16)o5}, h3 = {(f16)o6, (f16)o7};
        uint4 outw = make_uint4(h2u(h0), h2u(h1), h2u(h2), h2u(h3));
        h16[(size_t)node * 32 + l32] = outw;
    }
}

// ---------------- dueling heads (f16 feature tables) ----------------

__global__ __launch_bounds__(256) void head_kernel(
    const f16* __restrict__ hE16, const f16* __restrict__ hC1_16,
    const f16* __restrict__ hC2_16, const int* __restrict__ indices,
    const float* __restrict__ qw1, const float* __restrict__ qb1,
    const float* __restrict__ qw2, const float* __restrict__ qb2,
    const float* __restrict__ vw1, const float* __restrict__ vb1,
    const float* __restrict__ vw2, const float* __restrict__ vb2,
    float* __restrict__ out) {
    __shared__ float feat[576];
    __shared__ float red[384];
    int b = blockIdx.x;
    int t = threadIdx.x;
    int node = indices[b];
    for (int i = t; i < 576; i += 256) {
        float f;
        if (i < 64) f = (float)hE16[(size_t)node * 64 + i];
        else if (i < 320) f = (float)hC1_16[(size_t)node * 256 + i - 64];
        else f = (float)hC2_16[(size_t)node * 256 + i - 320];
        feat[i] = f;
    }
    __syncthreads();
    if (t < 128) {
        float aq = qb1[t];
        for (int k = 0; k < 576; ++k)
            aq = fmaf(feat[k], qw1[k * 128 + t], aq);
        aq = fmaxf(aq, 0.f);
        red[t]       = aq * qw2[t * 2 + 0];
        red[128 + t] = aq * qw2[t * 2 + 1];
    } else {
        int tv = t - 128;
        float av = vb1[tv];
        for (int k = 0; k < 576; ++k)
            av = fmaf(feat[k], vw1[k * 128 + tv], av);
        av = fmaxf(av, 0.f);
        red[256 + tv] = av * vw2[tv];
    }
    __syncthreads();
    for (int s = 64; s > 0; s >>= 1) {
        if (t < s) {
            red[t] += red[t + s];
            red[128 + t] += red[128 + t + s];
            red[256 + t] += red[256 + t + s];
        }
        __syncthreads();
    }
    if (t == 0) {
        float q0 = red[0] + qb2[0];
        float q1 = red[128] + qb2[1];
        float v  = red[256] + vb2[0];
        float mean = 0.5f * (q0 + q1);
        out[b * 2 + 0] = q0 - mean + v;
        out[b * 2 + 1] = q1 - mean + v;
    }
}

// ---------------- launch ----------------

extern "C" void kernel_launch(void* const* d_in, const int* in_sizes, int n_in,
                              void* d_out, int out_size, void* d_ws, size_t ws_size,
                              hipStream_t stream) {
    const float* x      = (const float*)d_in[0];
    const int*   ei     = (const int*)d_in[1];
    const int*   indices= (const int*)d_in[2];
    const float* enc_w1 = (const float*)d_in[3];
    const float* enc_b1 = (const float*)d_in[4];
    const float* enc_w2 = (const float*)d_in[5];
    const float* enc_b2 = (const float*)d_in[6];
    const float* wl1    = (const float*)d_in[7];
    const float* bl1    = (const float*)d_in[8];
    const float* wr1    = (const float*)d_in[9];
    const float* br1    = (const float*)d_in[10];
    const float* att1   = (const float*)d_in[11];
    const float* bias1  = (const float*)d_in[12];
    const float* wl2    = (const float*)d_in[13];
    const float* bl2    = (const float*)d_in[14];
    const float* wr2    = (const float*)d_in[15];
    const float* br2    = (const float*)d_in[16];
    const float* att2   = (const float*)d_in[17];
    const float* bias2  = (const float*)d_in[18];
    const float* qw1    = (const float*)d_in[19];
    const float* qb1    = (const float*)d_in[20];
    const float* qw2    = (const float*)d_in[21];
    const float* qb2    = (const float*)d_in[22];
    const float* vw1    = (const float*)d_in[23];
    const float* vb1    = (const float*)d_in[24];
    const float* vw2    = (const float*)d_in[25];
    const float* vb2    = (const float*)d_in[26];

    const int N = in_sizes[0] / IN_DIM;
    const int E = in_sizes[1] / 2;
    const int B = in_sizes[2];
    const int Etot = E + N;

    // ---- workspace arena ----
    char* wsb = (char*)d_ws;
    size_t off = 0;
    auto alloc = [&](size_t bytes) -> void* {
        void* p = wsb + off;
        off = (off + bytes + 255) & ~(size_t)255;
        return p;
    };
    f16* x16     = (f16*)alloc((size_t)N * 64 * 2);
    f16* h1_16   = (f16*)alloc((size_t)N * 512 * 2);
    f16* hE16    = (f16*)alloc((size_t)N * 64 * 2);
    f16* xl16    = (f16*)alloc((size_t)N * 256 * 2);
    f16* xr16    = (f16*)alloc((size_t)N * 256 * 2);
    f16* hC1_16  = (f16*)alloc((size_t)N * 256 * 2);
    f16* hC2_16  = (f16*)alloc((size_t)N * 256 * 2);
    f16* w1t     = (f16*)alloc((size_t)ENC_H * IN_DIM * 2);
    f16* w2t     = (f16*)alloc((size_t)HID * ENC_H * 2);
    f16* wcat1   = (f16*)alloc((size_t)512 * HID * 2);
    f16* wcat2   = (f16*)alloc((size_t)512 * DD * 2);
    int* counts  = (int*)alloc((size_t)(N + 1) * 4);
    int* offsets = (int*)alloc((size_t)(N + 1) * 4);
    int* cursor  = (int*)alloc((size_t)(N + 1) * 4);
    int* csr_src = (int*)alloc((size_t)Etot * 4);

    // ---- prep ----
    int nx4 = N * 16;
    int ntot = nx4 + 229376 + (N + 1);
    prep_all<<<(ntot + 255) / 256, 256, 0, stream>>>(
        (const float4*)x, (f16x4*)x16, nx4,
        enc_w1, enc_w2, wl1, wr1, wl2, wr2,
        w1t, w2t, wcat1, wcat2, counts, N + 1);

    int grows = (N + 63) / 64;          // 313
    int gemmB1 = 4 * grows;             // 1252 (BN=128 over 512 cols)
    int auxB = (Etot + 255) / 256;      // hist/scatter blocks

    // ---- enc1 + hist (both depend only on prep) ----
    enc1_hist_kernel<<<gemmB1 + auxB, 256, 0, stream>>>(
        x16, w1t, enc_b1, N, h1_16, gemmB1, ei, E, N, counts);

    // ---- enc2 + scan ----
    enc2_scan_kernel<<<grows + 1, 256, 0, stream>>>(
        h1_16, w2t, enc_b2, N, hE16, grows, counts, offsets, cursor, N);

    // ---- conv1 transform + scatter ----
    conv1t_scatter_kernel<<<gemmB1 + auxB, 256, 0, stream>>>(
        hE16, wcat1, bl1, br1, N, xl16, xr16, gemmB1, ei, E, N, cursor, csr_src);

    // ---- GAT 1 ----
    int gatg = (N * 64 + 255) / 256;
    gat_fused_kernel<<<gatg, 256, 0, stream>>>(
        (const uint4*)xl16, (const uint4*)xr16, (const float4*)att1,
        offsets, csr_src, (const float4*)bias1, (uint4*)hC1_16, N);

    // ---- conv2 transform + GAT 2 ----
    gemm_slab<256, 128><<<dim3(4, grows), dim3(256), 0, stream>>>(
        hC1_16, wcat2, bl2, br2, DD, N, 0, xl16, xr16);
    gat_fused_kernel<<<gatg, 256, 0, stream>>>(
        (const uint4*)xl16, (const uint4*)xr16, (const float4*)att2,
        offsets, csr_src, (const float4*)bias2, (uint4*)hC2_16, N);

    // ---- dueling heads ----
    head_kernel<<<B, 256, 0, stream>>>(hE16, hC1_16, hC2_16, indices,
                                       qw1, qb1, qw2, qb2, vw1, vb1, vw2, vb2,
                                       (float*)d_out);
}